// Round 4
// baseline (350.052 us; speedup 1.0000x reference)
//
#include <hip/hip_runtime.h>
#include <hip/hip_bf16.h>

#define T_SEQ 2048
#define D_MODEL 2048
#define NH 16
#define NKVH 4
#define HD 128

typedef __attribute__((ext_vector_type(8))) short bf16x8;
typedef __attribute__((ext_vector_type(4))) float f32x4;

static __device__ __forceinline__ short f32_to_bf16(float f) {
    unsigned u = __float_as_uint(f);
    u += 0x7fffu + ((u >> 16) & 1u);
    return (short)(u >> 16);
}
static __device__ __forceinline__ float bf16_to_f32(short s) {
    return __uint_as_float(((unsigned)(unsigned short)s) << 16);
}
static __device__ __forceinline__ void gl_to_lds16(const void* g, void* l) {
    __builtin_amdgcn_global_load_lds(
        (const __attribute__((address_space(1))) unsigned int*)g,
        (__attribute__((address_space(3))) unsigned int*)l, 16, 0, 0);
}

// ---------------------------------------------------------------------------
// Pipelined GEMM, R4-proven loop (dbuf, vmcnt(0)+barrier, prefetch-after-
// barrier, xor-swizzle) but BM=64 so grid = (N/BN)*(M/64) = 512 blocks
// = 2 blocks/CU: inter-block wave overlap absorbs the barrier drain that
// capped every 1-block/CU variant (R3/R4/R6/R7) at ~2us/iter.
// BN=128: wave = 64x32 (NI=2). BN=64: wave = 64x16 (NI=1). LDS 48/32 KB.
// ---------------------------------------------------------------------------
template<int BN>
__global__ __launch_bounds__(256, 2) void gemm_bt_kernel(
    const short* __restrict__ A, const short* __restrict__ Bt,
    float* __restrict__ Cf, short* __restrict__ Cb,
    int M, int N, int K, const float* __restrict__ bias, int act)
{
    constexpr int NI = BN / 64;                // 2 or 1
    constexpr int BCH = BN / 32;               // B staging instrs/wave (4 or 2)
    __shared__ short Alds[2][64 * 64];
    __shared__ short Blds[2][BN * 64];

    const int tid = threadIdx.x;
    const int wave = tid >> 6, lane = tid & 63;
    const int l16 = lane & 15, quad = lane >> 4;
    const int wn = wave * (BN / 4);
    const int m0 = blockIdx.y * 64, n0 = blockIdx.x * BN;
    const int niter = K >> 6;

    f32x4 acc[4][NI] = {};

    #pragma unroll
    for (int p = 0; p < 2; ++p) {
        int li = p * 256 + tid;
        int row = li >> 3, sc = li & 7;
        gl_to_lds16(A + (size_t)(m0 + row) * K + ((sc ^ (row & 7)) * 8),
                    &Alds[0][(size_t)(p * 256 + wave * 64) * 8]);
    }
    #pragma unroll
    for (int p = 0; p < BCH; ++p) {
        int li = p * 256 + tid;
        int row = li >> 3, sc = li & 7;
        gl_to_lds16(Bt + (size_t)(n0 + row) * K + ((sc ^ (row & 7)) * 8),
                    &Blds[0][(size_t)(p * 256 + wave * 64) * 8]);
    }

    for (int t = 0; t < niter; ++t) {
        asm volatile("s_waitcnt vmcnt(0)\n\ts_barrier" ::: "memory");

        if (t + 1 < niter) {               // prefetch overlaps compute below
            int k1 = (t + 1) << 6;
            int nb = (t + 1) & 1;
            #pragma unroll
            for (int p = 0; p < 2; ++p) {
                int li = p * 256 + tid;
                int row = li >> 3, sc = li & 7;
                gl_to_lds16(A + (size_t)(m0 + row) * K + k1 + ((sc ^ (row & 7)) * 8),
                            &Alds[nb][(size_t)(p * 256 + wave * 64) * 8]);
            }
            #pragma unroll
            for (int p = 0; p < BCH; ++p) {
                int li = p * 256 + tid;
                int row = li >> 3, sc = li & 7;
                gl_to_lds16(Bt + (size_t)(n0 + row) * K + k1 + ((sc ^ (row & 7)) * 8),
                            &Blds[nb][(size_t)(p * 256 + wave * 64) * 8]);
            }
        }

        const short* Ab = Alds[t & 1];
        const short* Bb = Blds[t & 1];
        #pragma unroll
        for (int kk = 0; kk < 2; ++kk) {
            bf16x8 a[4], b[NI];
            #pragma unroll
            for (int i = 0; i < 4; ++i)
                a[i] = *(const bf16x8*)
                    &Ab[(size_t)(i * 16 + l16) * 64 + (((kk * 4 + quad) ^ (l16 & 7)) * 8)];
            #pragma unroll
            for (int i = 0; i < NI; ++i)
                b[i] = *(const bf16x8*)
                    &Bb[(size_t)(wn + i * 16 + l16) * 64 + (((kk * 4 + quad) ^ (l16 & 7)) * 8)];
            #pragma unroll
            for (int mi = 0; mi < 4; ++mi)
                #pragma unroll
                for (int ni = 0; ni < NI; ++ni)
                    acc[mi][ni] = __builtin_amdgcn_mfma_f32_16x16x32_bf16(
                        a[mi], b[ni], acc[mi][ni], 0, 0, 0);
        }
    }

    #pragma unroll
    for (int mi = 0; mi < 4; ++mi) {
        #pragma unroll
        for (int ni = 0; ni < NI; ++ni) {
            int col = n0 + wn + ni * 16 + l16;
            float bv = bias ? bias[col] : 0.0f;
            #pragma unroll
            for (int r = 0; r < 4; ++r) {
                int row = m0 + mi * 16 + quad * 4 + r;
                float x = acc[mi][ni][r] + bv;
                if (act) x = x / (1.0f + __expf(-x));
                size_t o = (size_t)row * N + col;
                if (Cf) Cf[o] = x;
                if (Cb) Cb[o] = f32_to_bf16(x);
            }
        }
    }
}

// ---------------------------------------------------------------------------
// All 5 weight transposes in one launch. fp32 (2048 x C) -> bf16 (C x 2048).
// ---------------------------------------------------------------------------
__global__ __launch_bounds__(256) void transpose_all_kernel(
    const float* __restrict__ Wq, const float* __restrict__ Wk,
    const float* __restrict__ Wv, const float* __restrict__ Wr1,
    const float* __restrict__ Wo, short* __restrict__ Wq_t,
    short* __restrict__ Wkv_t, short* __restrict__ Wr1_t,
    short* __restrict__ Wo_t)
{
    __shared__ float tile[32][33];
    int bx = blockIdx.x;
    const float* src; short* dst; int ld, cb;
    if (bx < 64)       { src = Wq;  dst = Wq_t;  ld = 2048; cb = bx; }
    else if (bx < 80)  { src = Wk;  dst = Wkv_t; ld = 512;  cb = bx - 64; }
    else if (bx < 96)  { src = Wv;  dst = Wkv_t + (size_t)512 * 2048; ld = 512; cb = bx - 80; }
    else if (bx < 128) { src = Wr1; dst = Wr1_t; ld = 1024; cb = bx - 96; }
    else               { src = Wo;  dst = Wo_t;  ld = 2048; cb = bx - 128; }
    int c0 = cb * 32, r0 = blockIdx.y * 32;
    int t = threadIdx.x;
    int r = t >> 3, c4 = (t & 7) * 4;
    float4 v = *(const float4*)&src[(size_t)(r0 + r) * ld + c0 + c4];
    tile[r][c4 + 0] = v.x; tile[r][c4 + 1] = v.y;
    tile[r][c4 + 2] = v.z; tile[r][c4 + 3] = v.w;
    __syncthreads();
    short o[4];
    #pragma unroll
    for (int j = 0; j < 4; ++j) o[j] = f32_to_bf16(tile[c4 + j][r]);
    *(uint2*)&dst[(size_t)(c0 + r) * 2048 + r0 + c4] = *(const uint2*)o;
}

// bf16 transpose: src (R x C, ld) -> dst (C x R, ldd). grid (C/32, R/32).
__global__ __launch_bounds__(256) void transpose_bf_kernel(
    const short* __restrict__ src, int ld, short* __restrict__ dst, int ldd)
{
    __shared__ float tile[32][33];
    int r0 = blockIdx.y * 32, c0 = blockIdx.x * 32;
    int x = threadIdx.x & 31, y = threadIdx.x >> 5;
    #pragma unroll
    for (int i = 0; i < 4; ++i)
        tile[y + i * 8][x] = bf16_to_f32(src[(size_t)(r0 + y + i * 8) * ld + c0 + x]);
    __syncthreads();
    #pragma unroll
    for (int i = 0; i < 4; ++i)
        dst[(size_t)(c0 + y + i * 8) * ldd + r0 + x] = f32_to_bf16(tile[x][y + i * 8]);
}

// ---------------------------------------------------------------------------
// Causal prefix EMA (windowed, beta^192~2e-9) + hs -> bf16 conversion.
// ---------------------------------------------------------------------------
__global__ __launch_bounds__(256) void ema_kernel(const float* __restrict__ hs,
                                                  float* __restrict__ l2,
                                                  short* __restrict__ hs_b)
{
    int d = blockIdx.y * 256 + threadIdx.x;
    int t0 = blockIdx.x * 128;
    int ts = t0 - 192; if (ts < 0) ts = 0;
    float m = 0.0f;
    for (int tb = ts; tb < t0; tb += 16) {
        float buf[16];
        #pragma unroll
        for (int j = 0; j < 16; ++j) buf[j] = hs[(size_t)(tb + j) * D_MODEL + d];
        #pragma unroll
        for (int j = 0; j < 16; ++j) m = 0.9f * m + 0.1f * buf[j];
    }
    for (int tb = t0; tb < t0 + 128; tb += 16) {
        float buf[16];
        #pragma unroll
        for (int j = 0; j < 16; ++j) buf[j] = hs[(size_t)(tb + j) * D_MODEL + d];
        #pragma unroll
        for (int j = 0; j < 16; ++j) hs_b[(size_t)(tb + j) * D_MODEL + d] = f32_to_bf16(buf[j]);
        #pragma unroll
        for (int j = 0; j < 16; ++j) { m = 0.9f * m + 0.1f * buf[j]; buf[j] = m; }
        #pragma unroll
        for (int j = 0; j < 16; ++j) l2[(size_t)(tb + j) * D_MODEL + d] = buf[j];
    }
}

// Router head: logits = h @ Wr2 + br2, 2-way softmax. 1 wave/row.
__global__ __launch_bounds__(64) void lam_kernel(
    const short* __restrict__ h, const float* __restrict__ Wr2,
    const float* __restrict__ br2, float* __restrict__ lam)
{
    int t = blockIdx.x;
    int lane = threadIdx.x;
    float z0 = 0.0f, z1 = 0.0f;
    for (int i = lane; i < 1024; i += 64) {
        float hv = bf16_to_f32(h[(size_t)t * 1024 + i]);
        z0 += hv * Wr2[i * 2 + 0];
        z1 += hv * Wr2[i * 2 + 1];
    }
    #pragma unroll
    for (int off = 1; off < 64; off <<= 1) {
        z0 += __shfl_xor(z0, off);
        z1 += __shfl_xor(z1, off);
    }
    if (lane == 0) {
        z0 += br2[0]; z1 += br2[1];
        float mx = fmaxf(z0, z1);
        float e0 = expf(z0 - mx), e1 = expf(z1 - mx);
        float inv = 1.0f / (e0 + e1);
        lam[t * 2 + 0] = e0 * inv;
        lam[t * 2 + 1] = e1 * inv;
    }
}

// fused = lam0*hs + lam1*l2 -> bf16
__global__ void fuse_kernel(const float* __restrict__ hs, const float* __restrict__ l2,
                            const float* __restrict__ lam, short* __restrict__ fused)
{
    int idx = blockIdx.x * blockDim.x + threadIdx.x;
    int t = idx >> 9;
    float a0 = lam[t * 2 + 0], a1 = lam[t * 2 + 1];
    float4 a = ((const float4*)hs)[idx];
    float4 b = ((const float4*)l2)[idx];
    short o[4] = {f32_to_bf16(a0 * a.x + a1 * b.x), f32_to_bf16(a0 * a.y + a1 * b.y),
                  f32_to_bf16(a0 * a.z + a1 * b.z), f32_to_bf16(a0 * a.w + a1 * b.w)};
    *(uint2*)(fused + (size_t)idx * 4) = *(const uint2*)o;
}

// RoPE on q -> (H, T, HD) bf16, with 1/sqrt(HD) folded in.
__global__ void rope_q_kernel(const short* __restrict__ q, short* __restrict__ qr)
{
    int idx = blockIdx.x * blockDim.x + threadIdx.x;   // T*NH*64
    int d = idx & 63;
    int h = (idx >> 6) & 15;
    int t = idx >> 10;
    float fr = (float)t * __expf(-(float)d * 0.14391156831212787f);
    float s, c;
    sincosf(fr, &s, &c);
    const float sc = 0.08838834764831845f;  // 1/sqrt(128)
    const short* src = q + (size_t)t * D_MODEL + h * HD;
    float x1 = bf16_to_f32(src[d]) * sc, x2 = bf16_to_f32(src[d + 64]) * sc;
    short* dst = qr + ((size_t)h * T_SEQ + t) * HD;
    dst[d]      = f32_to_bf16(x1 * c - x2 * s);
    dst[d + 64] = f32_to_bf16(x2 * c + x1 * s);
}

// RoPE on k-half of kv (bf16 T x 1024) -> (KVH, T, HD) bf16.
__global__ void rope_k_kernel(const short* __restrict__ kv, short* __restrict__ kr)
{
    int idx = blockIdx.x * blockDim.x + threadIdx.x;   // T*NKVH*64
    int d = idx & 63;
    int kh = (idx >> 6) & 3;
    int t = idx >> 8;
    float fr = (float)t * __expf(-(float)d * 0.14391156831212787f);
    float s, c;
    sincosf(fr, &s, &c);
    const short* src = kv + (size_t)t * 1024 + kh * HD;
    float x1 = bf16_to_f32(src[d]), x2 = bf16_to_f32(src[d + 64]);
    short* dst = kr + ((size_t)kh * T_SEQ + t) * HD;
    dst[d]      = f32_to_bf16(x1 * c - x2 * s);
    dst[d + 64] = f32_to_bf16(x2 * c + x1 * s);
}

// ---------------------------------------------------------------------------
// Causal flash attention R4: LDS-bandwidth model. Measured R0/R3 iteration
// times match LDS traffic at ~100 B/cyc (R0: 352KB/iter=1.5us; R3: 620KB
// =3.4us): the kernel is LDS-BW-bound because each wave re-reads the FULL
// K and V tiles for only 16 q-rows. Fix: 32 q-rows/wave (two A-fragments
// per B-read) -> same K/V bytes feed 2x MFMAs. 4 waves x 32 rows = 128-row
// q-tile, KVBLK=128, grid (16 h, 16 qt) = 256 blocks = 1/CU. Per-iter CU
// traffic ~384KB per 128 rows = 3.0 KB/row vs R0 5.5 -> predict ~26-30us.
// Grid ordered (h, qt): XCD = h%8 -> 2 kvh (2MB) per XCD L2; the 16
// longest blocks (qt=15) spread 2 per XCD.
// ---------------------------------------------------------------------------
__global__ __launch_bounds__(256, 1) void attn_kernel(
    const short* __restrict__ Qr, const short* __restrict__ Kr,
    const short* __restrict__ Vt, short* __restrict__ Out)
{
    const int h = blockIdx.x;           // 0..15  (fast dim -> XCD = h%8)
    const int qt = blockIdx.y;          // 0..15, 128-row q tile
    const int kvh = h >> 2;
    const int tid = threadIdx.x;
    const int wave = tid >> 6, lane = tid & 63;
    const int l16 = lane & 15, quad = lane >> 4;

    __shared__ short Klds[2][128 * 128];   // 64 KB, xor-swizzled chunks
    __shared__ short Vlds[2][128 * 128];   // 64 KB, [hd][kv] swizzled
    __shared__ short Plds[4][32][128];     // 32 KB, chunk-xor swizzled per 16-row half

    const short* kbase = Kr + (size_t)kvh * T_SEQ * HD;
    const short* vbase = Vt + (size_t)kvh * HD * T_SEQ;

    const int qbase = qt * 128 + wave * 32;    // this wave's 32 q-rows
    const int n = qt + 1;                      // KV-128 tiles up to diagonal

    // Q fragments: 2 row-groups (m) x 4 k-chunks
    bf16x8 qf[2][4];
    #pragma unroll
    for (int m = 0; m < 2; ++m) {
        const short* qrow = Qr + ((size_t)h * T_SEQ + qbase + m * 16 + l16) * HD;
        #pragma unroll
        for (int kc = 0; kc < 4; ++kc)
            qf[m][kc] = *(const bf16x8*)&qrow[kc * 32 + quad * 8];
    }
    f32x4 o[2][8] = {};
    float lsum[2][4] = {};

    {   // stage tile 0: 128x128 shorts = 2048 16B-slots, 256 threads, 8 each
        #pragma unroll
        for (int p = 0; p < 8; ++p) {
            int li = p * 256 + tid;
            int row = li >> 4, gs = (li & 15) ^ (row & 15);
            gl_to_lds16(kbase + (size_t)row * HD + gs * 8,
                        &Klds[0][(size_t)(p * 256 + wave * 64) * 8]);
        }
        #pragma unroll
        for (int p = 0; p < 8; ++p) {
            int li = p * 256 + tid;
            int row = li >> 4, gs = (li & 15) ^ (row & 15);
            gl_to_lds16(vbase + (size_t)row * T_SEQ + gs * 8,
                        &Vlds[0][(size_t)(p * 256 + wave * 64) * 8]);
        }
    }

    for (int t = 0; t < n; ++t) {
        asm volatile("s_waitcnt vmcnt(0)\n\ts_barrier" ::: "memory");

        if (t + 1 < n) {   // prefetch next KV-128 tile; overlaps compute below
            int kv1 = (t + 1) << 7;
            int nb = (t + 1) & 1;
            const short* ks = kbase + (size_t)kv1 * HD;
            #pragma unroll
            for (int p = 0; p < 8; ++p) {
                int li = p * 256 + tid;
                int row = li >> 4, gs = (li & 15) ^ (row & 15);
                gl_to_lds16(ks + (size_t)row * HD + gs * 8,
                            &Klds[nb][(size_t)(p * 256 + wave * 64) * 8]);
            }
            #pragma unroll
            for (int p = 0; p < 8; ++p) {
                int li = p * 256 + tid;
                int row = li >> 4, gs = (li & 15) ^ (row & 15);
                gl_to_lds16(vbase + (size_t)row * T_SEQ + kv1 + gs * 8,
                            &Vlds[nb][(size_t)(p * 256 + wave * 64) * 8]);
            }
        }

        const short* Kb = Klds[t & 1];
        const short* Vb = Vlds[t & 1];

        // QK^T: one K-read feeds both row-groups (the LDS-traffic fix)
        f32x4 s[2][8];
        #pragma unroll
        for (int m = 0; m < 2; ++m)
            #pragma unroll
            for (int ni = 0; ni < 8; ++ni) s[m][ni] = (f32x4){0, 0, 0, 0};
        __builtin_amdgcn_s_setprio(1);
        #pragma unroll
        for (int ni = 0; ni < 8; ++ni)
            #pragma unroll
            for (int kc = 0; kc < 4; ++kc) {
                bf16x8 b = *(const bf16x8*)
                    &Kb[(size_t)(ni * 16 + l16) * 128 + (((kc * 4 + quad) ^ l16) * 8)];
                s[0][ni] = __builtin_amdgcn_mfma_f32_16x16x32_bf16(qf[0][kc], b, s[0][ni], 0, 0, 0);
                s[1][ni] = __builtin_amdgcn_mfma_f32_16x16x32_bf16(qf[1][kc], b, s[1][ni], 0, 0, 0);
            }
        __builtin_amdgcn_s_setprio(0);

        // softmax (max-free) -> Plds; 16B-chunk xor swizzle within 16-row half
        if (t == n - 1) {
            int kvg0 = t << 7;
            #pragma unroll
            for (int m = 0; m < 2; ++m)
                #pragma unroll
                for (int ni = 0; ni < 8; ++ni) {
                    int kvg = kvg0 + ni * 16 + l16;
                    #pragma unroll
                    for (int r = 0; r < 4; ++r) {
                        int qg = qbase + m * 16 + quad * 4 + r;
                        float p = (kvg <= qg) ? __expf(s[m][ni][r]) : 0.0f;
                        lsum[m][r] += p;
                        int prow = quad * 4 + r, pcol = ni * 16 + l16;
                        Plds[wave][m * 16 + prow][(((pcol >> 3) ^ prow) * 8) + (pcol & 7)] =
                            f32_to_bf16(p);
                    }
                }
        } else {
            #pragma unroll
            for (int m = 0; m < 2; ++m)
                #pragma unroll
                for (int ni = 0; ni < 8; ++ni)
                    #pragma unroll
                    for (int r = 0; r < 4; ++r) {
                        float p = __expf(s[m][ni][r]);
                        lsum[m][r] += p;
                        int prow = quad * 4 + r, pcol = ni * 16 + l16;
                        Plds[wave][m * 16 + prow][(((pcol >> 3) ^ prow) * 8) + (pcol & 7)] =
                            f32_to_bf16(p);
                    }
        }
        asm volatile("s_waitcnt lgkmcnt(0)" ::: "memory");

        // PV: one V-read feeds both row-groups
        __builtin_amdgcn_s_setprio(1);
        #pragma unroll
        for (int kc = 0; kc < 4; ++kc) {
            bf16x8 pa0 = *(const bf16x8*)
                &Plds[wave][l16][(((kc * 4 + quad) ^ l16) * 8)];
            bf16x8 pa1 = *(const bf16x8*)
                &Plds[wave][16 + l16][(((kc * 4 + quad) ^ l16) * 8)];
            #pragma unroll
            for (int d8 = 0; d8 < 8; ++d8) {
                bf16x8 b = *(const bf16x8*)
                    &Vb[(size_t)(d8 * 16 + l16) * 128 + (((kc * 4 + quad) ^ l16) * 8)];
                o[0][d8] = __builtin_amdgcn_mfma_f32_16x16x32_bf16(pa0, b, o[0][d8], 0, 0, 0);
                o[1][d8] = __builtin_amdgcn_mfma_f32_16x16x32_bf16(pa1, b, o[1][d8], 0, 0, 0);
            }
        }
        __builtin_amdgcn_s_setprio(0);
    }

    #pragma unroll
    for (int m = 0; m < 2; ++m)
        #pragma unroll
        for (int r = 0; r < 4; ++r) {
            #pragma unroll
            for (int off = 1; off < 16; off <<= 1)
                lsum[m][r] += __shfl_xor(lsum[m][r], off);
            lsum[m][r] = 1.0f / lsum[m][r];
        }
    #pragma unroll
    for (int m = 0; m < 2; ++m)
        #pragma unroll
        for (int d8 = 0; d8 < 8; ++d8)
            #pragma unroll
            for (int r = 0; r < 4; ++r) {
                int row = qbase + m * 16 + quad * 4 + r;
                Out[(size_t)row * D_MODEL + h * HD + d8 * 16 + l16] =
                    f32_to_bf16(o[m][d8][r] * lsum[m][r]);
            }
}

// ---------------------------------------------------------------------------
extern "C" void kernel_launch(void* const* d_in, const int* in_sizes, int n_in,
                              void* d_out, int out_size, void* d_ws, size_t ws_size,
                              hipStream_t stream)
{
    const float* hs  = (const float*)d_in[0];
    const float* Wq  = (const float*)d_in[1];
    const float* Wk  = (const float*)d_in[2];
    const float* Wv  = (const float*)d_in[3];
    const float* Wo  = (const float*)d_in[4];
    const float* Wr1 = (const float*)d_in[5];
    const float* br1 = (const float*)d_in[6];
    const float* Wr2 = (const float*)d_in[7];
    const float* br2 = (const float*)d_in[8];
    float* out = (float*)d_out;

    char* w = (char*)d_ws;
    const size_t MB = 1u << 20;
    float* l2_f     = (float*)(w + 0 * MB);    // 16 MB
    short* hs_bf    = (short*)(w + 16 * MB);   // 8 MB (aliased as attn_bf later)
    short* Wq_t     = (short*)(w + 24 * MB);   // 8 MB
    short* Wkv_t    = (short*)(w + 32 * MB);   // 4 MB  [Wk^T | Wv^T]
    short* Wr1_t    = (short*)(w + 36 * MB);   // 4 MB
    short* Wo_t     = (short*)(w + 40 * MB);   // 8 MB
    short* q_bf     = (short*)(w + 48 * MB);   // 8 MB
    short* h_bf     = (short*)(w + 56 * MB);   // 4 MB
    short* fused_bf = (short*)(w + 60 * MB);   // 8 MB
    short* kv_bf    = (short*)(w + 68 * MB);   // 4 MB
    short* qr       = (short*)(w + 72 * MB);   // 8 MB (H,T,HD), roped+scaled
    short* kr       = (short*)(w + 80 * MB);   // 2 MB (KVH,T,HD), roped
    short* vr       = (short*)(w + 82 * MB);   // 2 MB (KVH,HD,T)
    float* lam_f    = (float*)(w + 84 * MB);   // 16 KB
    short* attn_bf  = hs_bf;                   // alias: hs_bf dead after q-gemm

    transpose_all_kernel<<<dim3(192, 64), 256, 0, stream>>>(
        Wq, Wk, Wv, Wr1, Wo, Wq_t, Wkv_t, Wr1_t, Wo_t);

    ema_kernel<<<dim3(T_SEQ / 128, D_MODEL / 256), 256, 0, stream>>>(hs, l2_f, hs_bf);

    // q = hs @ Wq : 16 x 32 = 512 blocks (2/CU)
    gemm_bt_kernel<128><<<dim3(16, 32), 256, 0, stream>>>(
        hs_bf, Wq_t, nullptr, q_bf, 2048, 2048, 2048, nullptr, 0);

    // h = silu(q @ Wr1 + br1) : BN=64 -> 16 x 32 = 512 blocks
    gemm_bt_kernel<64><<<dim3(16, 32), 256, 0, stream>>>(
        q_bf, Wr1_t, nullptr, h_bf, 2048, 1024, 2048, br1, 1);

    lam_kernel<<<T_SEQ, 64, 0, stream>>>(h_bf, Wr2, br2, lam_f);

    fuse_kernel<<<(T_SEQ * D_MODEL / 4) / 256, 256, 0, stream>>>(hs, l2_f, lam_f, fused_bf);

    // [k|v] = fused @ [Wk|Wv] : BN=64 -> 512 blocks
    gemm_bt_kernel<64><<<dim3(16, 32), 256, 0, stream>>>(
        fused_bf, Wkv_t, nullptr, kv_bf, 2048, 1024, 2048, nullptr, 0);

    rope_q_kernel<<<(T_SEQ * NH * 64) / 256, 256, 0, stream>>>(q_bf, qr);
    rope_k_kernel<<<(T_SEQ * NKVH * 64) / 256, 256, 0, stream>>>(kv_bf, kr);
    transpose_bf_kernel<<<dim3(16, 64), 256, 0, stream>>>(kv_bf + 512, 1024, vr, 2048);

    // 4 waves x 32 q-rows, 128-row tiles: grid (16 heads, 16 q-tiles)
    attn_kernel<<<dim3(NH, 16), 256, 0, stream>>>(qr, kr, vr, attn_bf);

    // out = attn @ Wo : 512 blocks
    gemm_bt_kernel<128><<<dim3(16, 32), 256, 0, stream>>>(
        attn_bf, Wo_t, out, nullptr, 2048, 2048, 2048, nullptr, 0);
}

// Round 5
// 321.621 us; speedup vs baseline: 1.0884x; 1.0884x over previous
//
#include <hip/hip_runtime.h>
#include <hip/hip_bf16.h>

#define T_SEQ 2048
#define D_MODEL 2048
#define NH 16
#define NKVH 4
#define HD 128

typedef __attribute__((ext_vector_type(8))) short bf16x8;
typedef __attribute__((ext_vector_type(4))) float f32x4;

static __device__ __forceinline__ short f32_to_bf16(float f) {
    unsigned u = __float_as_uint(f);
    u += 0x7fffu + ((u >> 16) & 1u);
    return (short)(u >> 16);
}
static __device__ __forceinline__ float bf16_to_f32(short s) {
    return __uint_as_float(((unsigned)(unsigned short)s) << 16);
}
static __device__ __forceinline__ void gl_to_lds16(const void* g, void* l) {
    __builtin_amdgcn_global_load_lds(
        (const __attribute__((address_space(1))) unsigned int*)g,
        (__attribute__((address_space(3))) unsigned int*)l, 16, 0, 0);
}

// ---------------------------------------------------------------------------
// Pipelined GEMM, R4-proven loop (dbuf, vmcnt(0)+barrier, prefetch-after-
// barrier, xor-swizzle) but BM=64 so grid = (N/BN)*(M/64) = 512 blocks
// = 2 blocks/CU: inter-block wave overlap absorbs the barrier drain that
// capped every 1-block/CU variant (R3/R4/R6/R7) at ~2us/iter.
// BN=128: wave = 64x32 (NI=2). BN=64: wave = 64x16 (NI=1). LDS 48/32 KB.
// ---------------------------------------------------------------------------
template<int BN>
__global__ __launch_bounds__(256, 2) void gemm_bt_kernel(
    const short* __restrict__ A, const short* __restrict__ Bt,
    float* __restrict__ Cf, short* __restrict__ Cb,
    int M, int N, int K, const float* __restrict__ bias, int act)
{
    constexpr int NI = BN / 64;                // 2 or 1
    constexpr int BCH = BN / 32;               // B staging instrs/wave (4 or 2)
    __shared__ short Alds[2][64 * 64];
    __shared__ short Blds[2][BN * 64];

    const int tid = threadIdx.x;
    const int wave = tid >> 6, lane = tid & 63;
    const int l16 = lane & 15, quad = lane >> 4;
    const int wn = wave * (BN / 4);
    const int m0 = blockIdx.y * 64, n0 = blockIdx.x * BN;
    const int niter = K >> 6;

    f32x4 acc[4][NI] = {};

    #pragma unroll
    for (int p = 0; p < 2; ++p) {
        int li = p * 256 + tid;
        int row = li >> 3, sc = li & 7;
        gl_to_lds16(A + (size_t)(m0 + row) * K + ((sc ^ (row & 7)) * 8),
                    &Alds[0][(size_t)(p * 256 + wave * 64) * 8]);
    }
    #pragma unroll
    for (int p = 0; p < BCH; ++p) {
        int li = p * 256 + tid;
        int row = li >> 3, sc = li & 7;
        gl_to_lds16(Bt + (size_t)(n0 + row) * K + ((sc ^ (row & 7)) * 8),
                    &Blds[0][(size_t)(p * 256 + wave * 64) * 8]);
    }

    for (int t = 0; t < niter; ++t) {
        asm volatile("s_waitcnt vmcnt(0)\n\ts_barrier" ::: "memory");

        if (t + 1 < niter) {               // prefetch overlaps compute below
            int k1 = (t + 1) << 6;
            int nb = (t + 1) & 1;
            #pragma unroll
            for (int p = 0; p < 2; ++p) {
                int li = p * 256 + tid;
                int row = li >> 3, sc = li & 7;
                gl_to_lds16(A + (size_t)(m0 + row) * K + k1 + ((sc ^ (row & 7)) * 8),
                            &Alds[nb][(size_t)(p * 256 + wave * 64) * 8]);
            }
            #pragma unroll
            for (int p = 0; p < BCH; ++p) {
                int li = p * 256 + tid;
                int row = li >> 3, sc = li & 7;
                gl_to_lds16(Bt + (size_t)(n0 + row) * K + k1 + ((sc ^ (row & 7)) * 8),
                            &Blds[nb][(size_t)(p * 256 + wave * 64) * 8]);
            }
        }

        const short* Ab = Alds[t & 1];
        const short* Bb = Blds[t & 1];
        #pragma unroll
        for (int kk = 0; kk < 2; ++kk) {
            bf16x8 a[4], b[NI];
            #pragma unroll
            for (int i = 0; i < 4; ++i)
                a[i] = *(const bf16x8*)
                    &Ab[(size_t)(i * 16 + l16) * 64 + (((kk * 4 + quad) ^ (l16 & 7)) * 8)];
            #pragma unroll
            for (int i = 0; i < NI; ++i)
                b[i] = *(const bf16x8*)
                    &Bb[(size_t)(wn + i * 16 + l16) * 64 + (((kk * 4 + quad) ^ (l16 & 7)) * 8)];
            #pragma unroll
            for (int mi = 0; mi < 4; ++mi)
                #pragma unroll
                for (int ni = 0; ni < NI; ++ni)
                    acc[mi][ni] = __builtin_amdgcn_mfma_f32_16x16x32_bf16(
                        a[mi], b[ni], acc[mi][ni], 0, 0, 0);
        }
    }

    #pragma unroll
    for (int mi = 0; mi < 4; ++mi) {
        #pragma unroll
        for (int ni = 0; ni < NI; ++ni) {
            int col = n0 + wn + ni * 16 + l16;
            float bv = bias ? bias[col] : 0.0f;
            #pragma unroll
            for (int r = 0; r < 4; ++r) {
                int row = m0 + mi * 16 + quad * 4 + r;
                float x = acc[mi][ni][r] + bv;
                if (act) x = x / (1.0f + __expf(-x));
                size_t o = (size_t)row * N + col;
                if (Cf) Cf[o] = x;
                if (Cb) Cb[o] = f32_to_bf16(x);
            }
        }
    }
}

// ---------------------------------------------------------------------------
// All 5 weight transposes in one launch. fp32 (2048 x C) -> bf16 (C x 2048).
// ---------------------------------------------------------------------------
__global__ __launch_bounds__(256) void transpose_all_kernel(
    const float* __restrict__ Wq, const float* __restrict__ Wk,
    const float* __restrict__ Wv, const float* __restrict__ Wr1,
    const float* __restrict__ Wo, short* __restrict__ Wq_t,
    short* __restrict__ Wkv_t, short* __restrict__ Wr1_t,
    short* __restrict__ Wo_t)
{
    __shared__ float tile[32][33];
    int bx = blockIdx.x;
    const float* src; short* dst; int ld, cb;
    if (bx < 64)       { src = Wq;  dst = Wq_t;  ld = 2048; cb = bx; }
    else if (bx < 80)  { src = Wk;  dst = Wkv_t; ld = 512;  cb = bx - 64; }
    else if (bx < 96)  { src = Wv;  dst = Wkv_t + (size_t)512 * 2048; ld = 512; cb = bx - 80; }
    else if (bx < 128) { src = Wr1; dst = Wr1_t; ld = 1024; cb = bx - 96; }
    else               { src = Wo;  dst = Wo_t;  ld = 2048; cb = bx - 128; }
    int c0 = cb * 32, r0 = blockIdx.y * 32;
    int t = threadIdx.x;
    int r = t >> 3, c4 = (t & 7) * 4;
    float4 v = *(const float4*)&src[(size_t)(r0 + r) * ld + c0 + c4];
    tile[r][c4 + 0] = v.x; tile[r][c4 + 1] = v.y;
    tile[r][c4 + 2] = v.z; tile[r][c4 + 3] = v.w;
    __syncthreads();
    short o[4];
    #pragma unroll
    for (int j = 0; j < 4; ++j) o[j] = f32_to_bf16(tile[c4 + j][r]);
    *(uint2*)&dst[(size_t)(c0 + r) * 2048 + r0 + c4] = *(const uint2*)o;
}

// bf16 transpose: src (R x C, ld) -> dst (C x R, ldd). grid (C/32, R/32).
__global__ __launch_bounds__(256) void transpose_bf_kernel(
    const short* __restrict__ src, int ld, short* __restrict__ dst, int ldd)
{
    __shared__ float tile[32][33];
    int r0 = blockIdx.y * 32, c0 = blockIdx.x * 32;
    int x = threadIdx.x & 31, y = threadIdx.x >> 5;
    #pragma unroll
    for (int i = 0; i < 4; ++i)
        tile[y + i * 8][x] = bf16_to_f32(src[(size_t)(r0 + y + i * 8) * ld + c0 + x]);
    __syncthreads();
    #pragma unroll
    for (int i = 0; i < 4; ++i)
        dst[(size_t)(c0 + y + i * 8) * ldd + r0 + x] = f32_to_bf16(tile[x][y + i * 8]);
}

// ---------------------------------------------------------------------------
// Causal prefix EMA (windowed, beta^192~2e-9) + hs -> bf16 conversion.
// ---------------------------------------------------------------------------
__global__ __launch_bounds__(256) void ema_kernel(const float* __restrict__ hs,
                                                  float* __restrict__ l2,
                                                  short* __restrict__ hs_b)
{
    int d = blockIdx.y * 256 + threadIdx.x;
    int t0 = blockIdx.x * 128;
    int ts = t0 - 192; if (ts < 0) ts = 0;
    float m = 0.0f;
    for (int tb = ts; tb < t0; tb += 16) {
        float buf[16];
        #pragma unroll
        for (int j = 0; j < 16; ++j) buf[j] = hs[(size_t)(tb + j) * D_MODEL + d];
        #pragma unroll
        for (int j = 0; j < 16; ++j) m = 0.9f * m + 0.1f * buf[j];
    }
    for (int tb = t0; tb < t0 + 128; tb += 16) {
        float buf[16];
        #pragma unroll
        for (int j = 0; j < 16; ++j) buf[j] = hs[(size_t)(tb + j) * D_MODEL + d];
        #pragma unroll
        for (int j = 0; j < 16; ++j) hs_b[(size_t)(tb + j) * D_MODEL + d] = f32_to_bf16(buf[j]);
        #pragma unroll
        for (int j = 0; j < 16; ++j) { m = 0.9f * m + 0.1f * buf[j]; buf[j] = m; }
        #pragma unroll
        for (int j = 0; j < 16; ++j) l2[(size_t)(tb + j) * D_MODEL + d] = buf[j];
    }
}

// Router head: logits = h @ Wr2 + br2, 2-way softmax. 1 wave/row.
__global__ __launch_bounds__(64) void lam_kernel(
    const short* __restrict__ h, const float* __restrict__ Wr2,
    const float* __restrict__ br2, float* __restrict__ lam)
{
    int t = blockIdx.x;
    int lane = threadIdx.x;
    float z0 = 0.0f, z1 = 0.0f;
    for (int i = lane; i < 1024; i += 64) {
        float hv = bf16_to_f32(h[(size_t)t * 1024 + i]);
        z0 += hv * Wr2[i * 2 + 0];
        z1 += hv * Wr2[i * 2 + 1];
    }
    #pragma unroll
    for (int off = 1; off < 64; off <<= 1) {
        z0 += __shfl_xor(z0, off);
        z1 += __shfl_xor(z1, off);
    }
    if (lane == 0) {
        z0 += br2[0]; z1 += br2[1];
        float mx = fmaxf(z0, z1);
        float e0 = expf(z0 - mx), e1 = expf(z1 - mx);
        float inv = 1.0f / (e0 + e1);
        lam[t * 2 + 0] = e0 * inv;
        lam[t * 2 + 1] = e1 * inv;
    }
}

// fused = lam0*hs + lam1*l2 -> bf16
__global__ void fuse_kernel(const float* __restrict__ hs, const float* __restrict__ l2,
                            const float* __restrict__ lam, short* __restrict__ fused)
{
    int idx = blockIdx.x * blockDim.x + threadIdx.x;
    int t = idx >> 9;
    float a0 = lam[t * 2 + 0], a1 = lam[t * 2 + 1];
    float4 a = ((const float4*)hs)[idx];
    float4 b = ((const float4*)l2)[idx];
    short o[4] = {f32_to_bf16(a0 * a.x + a1 * b.x), f32_to_bf16(a0 * a.y + a1 * b.y),
                  f32_to_bf16(a0 * a.z + a1 * b.z), f32_to_bf16(a0 * a.w + a1 * b.w)};
    *(uint2*)(fused + (size_t)idx * 4) = *(const uint2*)o;
}

// RoPE on q -> (H, T, HD) bf16, with 1/sqrt(HD) folded in.
__global__ void rope_q_kernel(const short* __restrict__ q, short* __restrict__ qr)
{
    int idx = blockIdx.x * blockDim.x + threadIdx.x;   // T*NH*64
    int d = idx & 63;
    int h = (idx >> 6) & 15;
    int t = idx >> 10;
    float fr = (float)t * __expf(-(float)d * 0.14391156831212787f);
    float s, c;
    sincosf(fr, &s, &c);
    const float sc = 0.08838834764831845f;  // 1/sqrt(128)
    const short* src = q + (size_t)t * D_MODEL + h * HD;
    float x1 = bf16_to_f32(src[d]) * sc, x2 = bf16_to_f32(src[d + 64]) * sc;
    short* dst = qr + ((size_t)h * T_SEQ + t) * HD;
    dst[d]      = f32_to_bf16(x1 * c - x2 * s);
    dst[d + 64] = f32_to_bf16(x2 * c + x1 * s);
}

// RoPE on k-half of kv (bf16 T x 1024) -> (KVH, T, HD) bf16.
__global__ void rope_k_kernel(const short* __restrict__ kv, short* __restrict__ kr)
{
    int idx = blockIdx.x * blockDim.x + threadIdx.x;   // T*NKVH*64
    int d = idx & 63;
    int kh = (idx >> 6) & 3;
    int t = idx >> 8;
    float fr = (float)t * __expf(-(float)d * 0.14391156831212787f);
    float s, c;
    sincosf(fr, &s, &c);
    const short* src = kv + (size_t)t * 1024 + kh * HD;
    float x1 = bf16_to_f32(src[d]), x2 = bf16_to_f32(src[d + 64]);
    short* dst = kr + ((size_t)kh * T_SEQ + t) * HD;
    dst[d]      = f32_to_bf16(x1 * c - x2 * s);
    dst[d + 64] = f32_to_bf16(x2 * c + x1 * s);
}

// ---------------------------------------------------------------------------
// Causal flash attention R5: R3 shell (8 waves / 512 thr / KVBLK=128 dbuf /
// 160 KB LDS, proven swizzles) with the wave partition changed from
// (8 q-subsets x full KV) to (4 q-subsets x 2 KV-halves).
// Evidence: R3 counters -> per CU-iter: VALU ~2550cy, MFMA ~2000cy,
// iter 8160cy (~40% idle); busy part LDS-dominated (each wave re-read the
// full 64KB K/V for only 16 q-rows). Here each wave does 32 q-rows x 64 kv:
// same 64 MFMA/wave/iter but HALF the B-fragment reads (36KB vs 72KB).
// 2 waves/SIMD overlap preserved (R3-proven). Max-free softmax makes the
// KV-half merge a pure add through LDS once per block.
// ---------------------------------------------------------------------------
__global__ __launch_bounds__(512, 2) void attn_kernel(
    const short* __restrict__ Qr, const short* __restrict__ Kr,
    const short* __restrict__ Vt, short* __restrict__ Out)
{
    const int h = blockIdx.x;           // 0..15  (fast dim -> XCD spread)
    const int qt = blockIdx.y;          // 0..15, 128-row q tile
    const int kvh = h >> 2;
    const int tid = threadIdx.x;
    const int wave = tid >> 6, lane = tid & 63;
    const int l16 = lane & 15, quad = lane >> 4;
    const int wq = wave & 3;            // q-subset (32 rows)
    const int wk = wave >> 2;           // kv-half (64 cols)

    __shared__ __align__(16) char smem[163840];
    short* Klds = (short*)smem;               // [2][128*128]  64 KB
    short* Vlds = (short*)(smem + 65536);     // [2][128*128]  64 KB
    short* Plds = (short*)(smem + 131072);    // [8][32*64]    32 KB

    const short* kbase = Kr + (size_t)kvh * T_SEQ * HD;
    const short* vbase = Vt + (size_t)kvh * HD * T_SEQ;

    const int qbase = qt * 128 + wq * 32;
    const int ko = wk * 64;                    // this wave's kv-half
    const int n = qt + 1;                      // KV-128 tiles to diagonal

    bf16x8 qf[2][4];
    #pragma unroll
    for (int m = 0; m < 2; ++m) {
        const short* qrow = Qr + ((size_t)h * T_SEQ + qbase + m * 16 + l16) * HD;
        #pragma unroll
        for (int kc = 0; kc < 4; ++kc)
            qf[m][kc] = *(const bf16x8*)&qrow[kc * 32 + quad * 8];
    }
    f32x4 o[2][8] = {};
    float lsum[2][4] = {};

    {   // stage tile 0 (identical addressing to R3)
        #pragma unroll
        for (int p = 0; p < 4; ++p) {
            int li = p * 512 + tid;
            int row = li >> 4, gs = (li & 15) ^ (row & 15);
            gl_to_lds16(kbase + (size_t)row * HD + gs * 8,
                        &Klds[(size_t)(p * 512 + wave * 64) * 8]);
        }
        #pragma unroll
        for (int p = 0; p < 4; ++p) {
            int li = p * 512 + tid;
            int row = li >> 4, gs = (li & 15) ^ (row & 15);
            gl_to_lds16(vbase + (size_t)row * T_SEQ + gs * 8,
                        &Vlds[(size_t)(p * 512 + wave * 64) * 8]);
        }
    }

    for (int t = 0; t < n; ++t) {
        asm volatile("s_waitcnt vmcnt(0)\n\ts_barrier" ::: "memory");

        if (t + 1 < n) {   // prefetch next KV-128 tile
            int kv1 = (t + 1) << 7;
            int nb = (t + 1) & 1;
            const short* ks = kbase + (size_t)kv1 * HD;
            #pragma unroll
            for (int p = 0; p < 4; ++p) {
                int li = p * 512 + tid;
                int row = li >> 4, gs = (li & 15) ^ (row & 15);
                gl_to_lds16(ks + (size_t)row * HD + gs * 8,
                            &Klds[(size_t)(nb * 16384 + (p * 512 + wave * 64) * 8)]);
            }
            #pragma unroll
            for (int p = 0; p < 4; ++p) {
                int li = p * 512 + tid;
                int row = li >> 4, gs = (li & 15) ^ (row & 15);
                gl_to_lds16(vbase + (size_t)row * T_SEQ + kv1 + gs * 8,
                            &Vlds[(size_t)(nb * 16384 + (p * 512 + wave * 64) * 8)]);
            }
        }

        const short* Kb = Klds + (size_t)(t & 1) * 16384;
        const short* Vb = Vlds + (size_t)(t & 1) * 16384;

        // QK^T: 32 q-rows x this wave's 64 kv cols; one K-read -> 2 row-groups
        f32x4 s[2][4];
        #pragma unroll
        for (int m = 0; m < 2; ++m)
            #pragma unroll
            for (int ni = 0; ni < 4; ++ni) s[m][ni] = (f32x4){0, 0, 0, 0};
        __builtin_amdgcn_s_setprio(1);
        #pragma unroll
        for (int ni = 0; ni < 4; ++ni)
            #pragma unroll
            for (int kc = 0; kc < 4; ++kc) {
                bf16x8 b = *(const bf16x8*)
                    &Kb[(size_t)(ko + ni * 16 + l16) * 128 + (((kc * 4 + quad) ^ l16) * 8)];
                s[0][ni] = __builtin_amdgcn_mfma_f32_16x16x32_bf16(qf[0][kc], b, s[0][ni], 0, 0, 0);
                s[1][ni] = __builtin_amdgcn_mfma_f32_16x16x32_bf16(qf[1][kc], b, s[1][ni], 0, 0, 0);
            }
        __builtin_amdgcn_s_setprio(0);

        // softmax (max-free) -> Plds [32][64] per wave, chunk-xor swizzle
        if (t == n - 1) {
            int kvg0 = (t << 7) + ko;
            #pragma unroll
            for (int m = 0; m < 2; ++m)
                #pragma unroll
                for (int ni = 0; ni < 4; ++ni) {
                    int kvg = kvg0 + ni * 16 + l16;
                    #pragma unroll
                    for (int r = 0; r < 4; ++r) {
                        int qg = qbase + m * 16 + quad * 4 + r;
                        float p = (kvg <= qg) ? __expf(s[m][ni][r]) : 0.0f;
                        lsum[m][r] += p;
                        int prow = quad * 4 + r, pcol = ni * 16 + l16;
                        Plds[wave * 2048 + (m * 16 + prow) * 64 +
                             (((pcol >> 3) ^ (prow & 7)) * 8) + (pcol & 7)] = f32_to_bf16(p);
                    }
                }
        } else {
            #pragma unroll
            for (int m = 0; m < 2; ++m)
                #pragma unroll
                for (int ni = 0; ni < 4; ++ni)
                    #pragma unroll
                    for (int r = 0; r < 4; ++r) {
                        float p = __expf(s[m][ni][r]);
                        lsum[m][r] += p;
                        int prow = quad * 4 + r, pcol = ni * 16 + l16;
                        Plds[wave * 2048 + (m * 16 + prow) * 64 +
                             (((pcol >> 3) ^ (prow & 7)) * 8) + (pcol & 7)] = f32_to_bf16(p);
                    }
        }
        asm volatile("s_waitcnt lgkmcnt(0)" ::: "memory");

        // PV over this wave's kv-half: one V-read -> 2 row-groups
        __builtin_amdgcn_s_setprio(1);
        #pragma unroll
        for (int kc = 0; kc < 2; ++kc) {
            bf16x8 pa0 = *(const bf16x8*)
                &Plds[wave * 2048 + l16 * 64 + (((kc * 4 + quad) ^ (l16 & 7)) * 8)];
            bf16x8 pa1 = *(const bf16x8*)
                &Plds[wave * 2048 + (16 + l16) * 64 + (((kc * 4 + quad) ^ (l16 & 7)) * 8)];
            #pragma unroll
            for (int d8 = 0; d8 < 8; ++d8) {
                bf16x8 b = *(const bf16x8*)
                    &Vb[(size_t)(d8 * 16 + l16) * 128 +
                        (((wk * 8 + kc * 4 + quad) ^ l16) * 8)];
                o[0][d8] = __builtin_amdgcn_mfma_f32_16x16x32_bf16(pa0, b, o[0][d8], 0, 0, 0);
                o[1][d8] = __builtin_amdgcn_mfma_f32_16x16x32_bf16(pa1, b, o[1][d8], 0, 0, 0);
            }
        }
        __builtin_amdgcn_s_setprio(0);
    }

    // ---- merge the two kv-halves (max-free partials just add) ----
    __syncthreads();                         // all waves done with K/V LDS
    float* Ox = (float*)smem;                // [4][32][132] padded, 67584 B
    float* Lx = (float*)(smem + 67584);      // [4][32][16],  8192 B
    if (wk) {
        #pragma unroll
        for (int m = 0; m < 2; ++m)
            #pragma unroll
            for (int d8 = 0; d8 < 8; ++d8)
                #pragma unroll
                for (int r = 0; r < 4; ++r)
                    Ox[(wq * 32 + m * 16 + quad * 4 + r) * 132 + d8 * 16 + l16] = o[m][d8][r];
        #pragma unroll
        for (int m = 0; m < 2; ++m)
            #pragma unroll
            for (int r = 0; r < 4; ++r)
                Lx[(wq * 32 + m * 16 + quad * 4 + r) * 16 + l16] = lsum[m][r];
    }
    __syncthreads();
    if (!wk) {
        #pragma unroll
        for (int m = 0; m < 2; ++m)
            #pragma unroll
            for (int d8 = 0; d8 < 8; ++d8)
                #pragma unroll
                for (int r = 0; r < 4; ++r)
                    o[m][d8][r] += Ox[(wq * 32 + m * 16 + quad * 4 + r) * 132 + d8 * 16 + l16];
        #pragma unroll
        for (int m = 0; m < 2; ++m)
            #pragma unroll
            for (int r = 0; r < 4; ++r) {
                lsum[m][r] += Lx[(wq * 32 + m * 16 + quad * 4 + r) * 16 + l16];
                #pragma unroll
                for (int off = 1; off < 16; off <<= 1)
                    lsum[m][r] += __shfl_xor(lsum[m][r], off);
                lsum[m][r] = 1.0f / lsum[m][r];
            }
        #pragma unroll
        for (int m = 0; m < 2; ++m)
            #pragma unroll
            for (int d8 = 0; d8 < 8; ++d8)
                #pragma unroll
                for (int r = 0; r < 4; ++r) {
                    int row = qbase + m * 16 + quad * 4 + r;
                    Out[(size_t)row * D_MODEL + h * HD + d8 * 16 + l16] =
                        f32_to_bf16(o[m][d8][r] * lsum[m][r]);
                }
    }
}

// ---------------------------------------------------------------------------
extern "C" void kernel_launch(void* const* d_in, const int* in_sizes, int n_in,
                              void* d_out, int out_size, void* d_ws, size_t ws_size,
                              hipStream_t stream)
{
    const float* hs  = (const float*)d_in[0];
    const float* Wq  = (const float*)d_in[1];
    const float* Wk  = (const float*)d_in[2];
    const float* Wv  = (const float*)d_in[3];
    const float* Wo  = (const float*)d_in[4];
    const float* Wr1 = (const float*)d_in[5];
    const float* br1 = (const float*)d_in[6];
    const float* Wr2 = (const float*)d_in[7];
    const float* br2 = (const float*)d_in[8];
    float* out = (float*)d_out;

    char* w = (char*)d_ws;
    const size_t MB = 1u << 20;
    float* l2_f     = (float*)(w + 0 * MB);    // 16 MB
    short* hs_bf    = (short*)(w + 16 * MB);   // 8 MB (aliased as attn_bf later)
    short* Wq_t     = (short*)(w + 24 * MB);   // 8 MB
    short* Wkv_t    = (short*)(w + 32 * MB);   // 4 MB  [Wk^T | Wv^T]
    short* Wr1_t    = (short*)(w + 36 * MB);   // 4 MB
    short* Wo_t     = (short*)(w + 40 * MB);   // 8 MB
    short* q_bf     = (short*)(w + 48 * MB);   // 8 MB
    short* h_bf     = (short*)(w + 56 * MB);   // 4 MB
    short* fused_bf = (short*)(w + 60 * MB);   // 8 MB
    short* kv_bf    = (short*)(w + 68 * MB);   // 4 MB
    short* qr       = (short*)(w + 72 * MB);   // 8 MB (H,T,HD), roped+scaled
    short* kr       = (short*)(w + 80 * MB);   // 2 MB (KVH,T,HD), roped
    short* vr       = (short*)(w + 82 * MB);   // 2 MB (KVH,HD,T)
    float* lam_f    = (float*)(w + 84 * MB);   // 16 KB
    short* attn_bf  = hs_bf;                   // alias: hs_bf dead after q-gemm

    transpose_all_kernel<<<dim3(192, 64), 256, 0, stream>>>(
        Wq, Wk, Wv, Wr1, Wo, Wq_t, Wkv_t, Wr1_t, Wo_t);

    ema_kernel<<<dim3(T_SEQ / 128, D_MODEL / 256), 256, 0, stream>>>(hs, l2_f, hs_bf);

    // q = hs @ Wq : 16 x 32 = 512 blocks (2/CU)
    gemm_bt_kernel<128><<<dim3(16, 32), 256, 0, stream>>>(
        hs_bf, Wq_t, nullptr, q_bf, 2048, 2048, 2048, nullptr, 0);

    // h = silu(q @ Wr1 + br1) : BN=64 -> 16 x 32 = 512 blocks
    gemm_bt_kernel<64><<<dim3(16, 32), 256, 0, stream>>>(
        q_bf, Wr1_t, nullptr, h_bf, 2048, 1024, 2048, br1, 1);

    lam_kernel<<<T_SEQ, 64, 0, stream>>>(h_bf, Wr2, br2, lam_f);

    fuse_kernel<<<(T_SEQ * D_MODEL / 4) / 256, 256, 0, stream>>>(hs, l2_f, lam_f, fused_bf);

    // [k|v] = fused @ [Wk|Wv] : BN=64 -> 512 blocks
    gemm_bt_kernel<64><<<dim3(16, 32), 256, 0, stream>>>(
        fused_bf, Wkv_t, nullptr, kv_bf, 2048, 1024, 2048, nullptr, 0);

    rope_q_kernel<<<(T_SEQ * NH * 64) / 256, 256, 0, stream>>>(q_bf, qr);
    rope_k_kernel<<<(T_SEQ * NKVH * 64) / 256, 256, 0, stream>>>(kv_bf, kr);
    transpose_bf_kernel<<<dim3(16, 64), 256, 0, stream>>>(kv_bf + 512, 1024, vr, 2048);

    // 8 waves = (4 q-subsets x 2 kv-halves), grid (16 heads, 16 q-tiles)
    attn_kernel<<<dim3(NH, 16), 512, 0, stream>>>(qr, kr, vr, attn_bf);

    // out = attn @ Wo : 512 blocks
    gemm_bt_kernel<128><<<dim3(16, 32), 256, 0, stream>>>(
        attn_bf, Wo_t, out, nullptr, 2048, 2048, 2048, nullptr, 0);
}

// Round 6
// 314.668 us; speedup vs baseline: 1.1125x; 1.0221x over previous
//
#include <hip/hip_runtime.h>
#include <hip/hip_bf16.h>

#define T_SEQ 2048
#define D_MODEL 2048
#define NH 16
#define NKVH 4
#define HD 128

typedef __attribute__((ext_vector_type(8))) short bf16x8;
typedef __attribute__((ext_vector_type(4))) float f32x4;

static __device__ __forceinline__ short f32_to_bf16(float f) {
    unsigned u = __float_as_uint(f);
    u += 0x7fffu + ((u >> 16) & 1u);
    return (short)(u >> 16);
}
static __device__ __forceinline__ float bf16_to_f32(short s) {
    return __uint_as_float(((unsigned)(unsigned short)s) << 16);
}
static __device__ __forceinline__ void gl_to_lds16(const void* g, void* l) {
    __builtin_amdgcn_global_load_lds(
        (const __attribute__((address_space(1))) unsigned int*)g,
        (__attribute__((address_space(3))) unsigned int*)l, 16, 0, 0);
}

// ---------------------------------------------------------------------------
// Pipelined GEMM, R4-proven loop (dbuf, vmcnt(0)+barrier, prefetch-after-
// barrier, xor-swizzle) but BM=64 so grid = (N/BN)*(M/64) = 512 blocks
// = 2 blocks/CU: inter-block wave overlap absorbs the barrier drain that
// capped every 1-block/CU variant (R3/R4/R6/R7) at ~2us/iter.
// BN=128: wave = 64x32 (NI=2). BN=64: wave = 64x16 (NI=1). LDS 48/32 KB.
// ---------------------------------------------------------------------------
template<int BN>
__global__ __launch_bounds__(256, 2) void gemm_bt_kernel(
    const short* __restrict__ A, const short* __restrict__ Bt,
    float* __restrict__ Cf, short* __restrict__ Cb,
    int M, int N, int K, const float* __restrict__ bias, int act)
{
    constexpr int NI = BN / 64;                // 2 or 1
    constexpr int BCH = BN / 32;               // B staging instrs/wave (4 or 2)
    __shared__ short Alds[2][64 * 64];
    __shared__ short Blds[2][BN * 64];

    const int tid = threadIdx.x;
    const int wave = tid >> 6, lane = tid & 63;
    const int l16 = lane & 15, quad = lane >> 4;
    const int wn = wave * (BN / 4);
    const int m0 = blockIdx.y * 64, n0 = blockIdx.x * BN;
    const int niter = K >> 6;

    f32x4 acc[4][NI] = {};

    #pragma unroll
    for (int p = 0; p < 2; ++p) {
        int li = p * 256 + tid;
        int row = li >> 3, sc = li & 7;
        gl_to_lds16(A + (size_t)(m0 + row) * K + ((sc ^ (row & 7)) * 8),
                    &Alds[0][(size_t)(p * 256 + wave * 64) * 8]);
    }
    #pragma unroll
    for (int p = 0; p < BCH; ++p) {
        int li = p * 256 + tid;
        int row = li >> 3, sc = li & 7;
        gl_to_lds16(Bt + (size_t)(n0 + row) * K + ((sc ^ (row & 7)) * 8),
                    &Blds[0][(size_t)(p * 256 + wave * 64) * 8]);
    }

    for (int t = 0; t < niter; ++t) {
        asm volatile("s_waitcnt vmcnt(0)\n\ts_barrier" ::: "memory");

        if (t + 1 < niter) {               // prefetch overlaps compute below
            int k1 = (t + 1) << 6;
            int nb = (t + 1) & 1;
            #pragma unroll
            for (int p = 0; p < 2; ++p) {
                int li = p * 256 + tid;
                int row = li >> 3, sc = li & 7;
                gl_to_lds16(A + (size_t)(m0 + row) * K + k1 + ((sc ^ (row & 7)) * 8),
                            &Alds[nb][(size_t)(p * 256 + wave * 64) * 8]);
            }
            #pragma unroll
            for (int p = 0; p < BCH; ++p) {
                int li = p * 256 + tid;
                int row = li >> 3, sc = li & 7;
                gl_to_lds16(Bt + (size_t)(n0 + row) * K + k1 + ((sc ^ (row & 7)) * 8),
                            &Blds[nb][(size_t)(p * 256 + wave * 64) * 8]);
            }
        }

        const short* Ab = Alds[t & 1];
        const short* Bb = Blds[t & 1];
        #pragma unroll
        for (int kk = 0; kk < 2; ++kk) {
            bf16x8 a[4], b[NI];
            #pragma unroll
            for (int i = 0; i < 4; ++i)
                a[i] = *(const bf16x8*)
                    &Ab[(size_t)(i * 16 + l16) * 64 + (((kk * 4 + quad) ^ (l16 & 7)) * 8)];
            #pragma unroll
            for (int i = 0; i < NI; ++i)
                b[i] = *(const bf16x8*)
                    &Bb[(size_t)(wn + i * 16 + l16) * 64 + (((kk * 4 + quad) ^ (l16 & 7)) * 8)];
            #pragma unroll
            for (int mi = 0; mi < 4; ++mi)
                #pragma unroll
                for (int ni = 0; ni < NI; ++ni)
                    acc[mi][ni] = __builtin_amdgcn_mfma_f32_16x16x32_bf16(
                        a[mi], b[ni], acc[mi][ni], 0, 0, 0);
        }
    }

    #pragma unroll
    for (int mi = 0; mi < 4; ++mi) {
        #pragma unroll
        for (int ni = 0; ni < NI; ++ni) {
            int col = n0 + wn + ni * 16 + l16;
            float bv = bias ? bias[col] : 0.0f;
            #pragma unroll
            for (int r = 0; r < 4; ++r) {
                int row = m0 + mi * 16 + quad * 4 + r;
                float x = acc[mi][ni][r] + bv;
                if (act) x = x / (1.0f + __expf(-x));
                size_t o = (size_t)row * N + col;
                if (Cf) Cf[o] = x;
                if (Cb) Cb[o] = f32_to_bf16(x);
            }
        }
    }
}

// ---------------------------------------------------------------------------
// All 5 weight transposes in one launch. fp32 (2048 x C) -> bf16 (C x 2048).
// ---------------------------------------------------------------------------
__global__ __launch_bounds__(256) void transpose_all_kernel(
    const float* __restrict__ Wq, const float* __restrict__ Wk,
    const float* __restrict__ Wv, const float* __restrict__ Wr1,
    const float* __restrict__ Wo, short* __restrict__ Wq_t,
    short* __restrict__ Wkv_t, short* __restrict__ Wr1_t,
    short* __restrict__ Wo_t)
{
    __shared__ float tile[32][33];
    int bx = blockIdx.x;
    const float* src; short* dst; int ld, cb;
    if (bx < 64)       { src = Wq;  dst = Wq_t;  ld = 2048; cb = bx; }
    else if (bx < 80)  { src = Wk;  dst = Wkv_t; ld = 512;  cb = bx - 64; }
    else if (bx < 96)  { src = Wv;  dst = Wkv_t + (size_t)512 * 2048; ld = 512; cb = bx - 80; }
    else if (bx < 128) { src = Wr1; dst = Wr1_t; ld = 1024; cb = bx - 96; }
    else               { src = Wo;  dst = Wo_t;  ld = 2048; cb = bx - 128; }
    int c0 = cb * 32, r0 = blockIdx.y * 32;
    int t = threadIdx.x;
    int r = t >> 3, c4 = (t & 7) * 4;
    float4 v = *(const float4*)&src[(size_t)(r0 + r) * ld + c0 + c4];
    tile[r][c4 + 0] = v.x; tile[r][c4 + 1] = v.y;
    tile[r][c4 + 2] = v.z; tile[r][c4 + 3] = v.w;
    __syncthreads();
    short o[4];
    #pragma unroll
    for (int j = 0; j < 4; ++j) o[j] = f32_to_bf16(tile[c4 + j][r]);
    *(uint2*)&dst[(size_t)(c0 + r) * 2048 + r0 + c4] = *(const uint2*)o;
}

// bf16 transpose: src (R x C, ld) -> dst (C x R, ldd). grid (C/32, R/32).
__global__ __launch_bounds__(256) void transpose_bf_kernel(
    const short* __restrict__ src, int ld, short* __restrict__ dst, int ldd)
{
    __shared__ float tile[32][33];
    int r0 = blockIdx.y * 32, c0 = blockIdx.x * 32;
    int x = threadIdx.x & 31, y = threadIdx.x >> 5;
    #pragma unroll
    for (int i = 0; i < 4; ++i)
        tile[y + i * 8][x] = bf16_to_f32(src[(size_t)(r0 + y + i * 8) * ld + c0 + x]);
    __syncthreads();
    #pragma unroll
    for (int i = 0; i < 4; ++i)
        dst[(size_t)(c0 + y + i * 8) * ldd + r0 + x] = f32_to_bf16(tile[x][y + i * 8]);
}

// ---------------------------------------------------------------------------
// Causal prefix EMA (windowed, beta^192~2e-9) + hs -> bf16 conversion.
// ---------------------------------------------------------------------------
__global__ __launch_bounds__(256) void ema_kernel(const float* __restrict__ hs,
                                                  float* __restrict__ l2,
                                                  short* __restrict__ hs_b)
{
    int d = blockIdx.y * 256 + threadIdx.x;
    int t0 = blockIdx.x * 128;
    int ts = t0 - 192; if (ts < 0) ts = 0;
    float m = 0.0f;
    for (int tb = ts; tb < t0; tb += 16) {
        float buf[16];
        #pragma unroll
        for (int j = 0; j < 16; ++j) buf[j] = hs[(size_t)(tb + j) * D_MODEL + d];
        #pragma unroll
        for (int j = 0; j < 16; ++j) m = 0.9f * m + 0.1f * buf[j];
    }
    for (int tb = t0; tb < t0 + 128; tb += 16) {
        float buf[16];
        #pragma unroll
        for (int j = 0; j < 16; ++j) buf[j] = hs[(size_t)(tb + j) * D_MODEL + d];
        #pragma unroll
        for (int j = 0; j < 16; ++j) hs_b[(size_t)(tb + j) * D_MODEL + d] = f32_to_bf16(buf[j]);
        #pragma unroll
        for (int j = 0; j < 16; ++j) { m = 0.9f * m + 0.1f * buf[j]; buf[j] = m; }
        #pragma unroll
        for (int j = 0; j < 16; ++j) l2[(size_t)(tb + j) * D_MODEL + d] = buf[j];
    }
}

// Router head: logits = h @ Wr2 + br2, 2-way softmax. 1 wave/row.
__global__ __launch_bounds__(64) void lam_kernel(
    const short* __restrict__ h, const float* __restrict__ Wr2,
    const float* __restrict__ br2, float* __restrict__ lam)
{
    int t = blockIdx.x;
    int lane = threadIdx.x;
    float z0 = 0.0f, z1 = 0.0f;
    for (int i = lane; i < 1024; i += 64) {
        float hv = bf16_to_f32(h[(size_t)t * 1024 + i]);
        z0 += hv * Wr2[i * 2 + 0];
        z1 += hv * Wr2[i * 2 + 1];
    }
    #pragma unroll
    for (int off = 1; off < 64; off <<= 1) {
        z0 += __shfl_xor(z0, off);
        z1 += __shfl_xor(z1, off);
    }
    if (lane == 0) {
        z0 += br2[0]; z1 += br2[1];
        float mx = fmaxf(z0, z1);
        float e0 = expf(z0 - mx), e1 = expf(z1 - mx);
        float inv = 1.0f / (e0 + e1);
        lam[t * 2 + 0] = e0 * inv;
        lam[t * 2 + 1] = e1 * inv;
    }
}

// fused = lam0*hs + lam1*l2 -> bf16
__global__ void fuse_kernel(const float* __restrict__ hs, const float* __restrict__ l2,
                            const float* __restrict__ lam, short* __restrict__ fused)
{
    int idx = blockIdx.x * blockDim.x + threadIdx.x;
    int t = idx >> 9;
    float a0 = lam[t * 2 + 0], a1 = lam[t * 2 + 1];
    float4 a = ((const float4*)hs)[idx];
    float4 b = ((const float4*)l2)[idx];
    short o[4] = {f32_to_bf16(a0 * a.x + a1 * b.x), f32_to_bf16(a0 * a.y + a1 * b.y),
                  f32_to_bf16(a0 * a.z + a1 * b.z), f32_to_bf16(a0 * a.w + a1 * b.w)};
    *(uint2*)(fused + (size_t)idx * 4) = *(const uint2*)o;
}

// RoPE on q -> (H, T, HD) bf16, with 1/sqrt(HD) folded in.
__global__ void rope_q_kernel(const short* __restrict__ q, short* __restrict__ qr)
{
    int idx = blockIdx.x * blockDim.x + threadIdx.x;   // T*NH*64
    int d = idx & 63;
    int h = (idx >> 6) & 15;
    int t = idx >> 10;
    float fr = (float)t * __expf(-(float)d * 0.14391156831212787f);
    float s, c;
    sincosf(fr, &s, &c);
    const float sc = 0.08838834764831845f;  // 1/sqrt(128)
    const short* src = q + (size_t)t * D_MODEL + h * HD;
    float x1 = bf16_to_f32(src[d]) * sc, x2 = bf16_to_f32(src[d + 64]) * sc;
    short* dst = qr + ((size_t)h * T_SEQ + t) * HD;
    dst[d]      = f32_to_bf16(x1 * c - x2 * s);
    dst[d + 64] = f32_to_bf16(x2 * c + x1 * s);
}

// RoPE on k-half of kv (bf16 T x 1024) -> (KVH, T, HD) bf16.
__global__ void rope_k_kernel(const short* __restrict__ kv, short* __restrict__ kr)
{
    int idx = blockIdx.x * blockDim.x + threadIdx.x;   // T*NKVH*64
    int d = idx & 63;
    int kh = (idx >> 6) & 3;
    int t = idx >> 8;
    float fr = (float)t * __expf(-(float)d * 0.14391156831212787f);
    float s, c;
    sincosf(fr, &s, &c);
    const short* src = kv + (size_t)t * 1024 + kh * HD;
    float x1 = bf16_to_f32(src[d]), x2 = bf16_to_f32(src[d + 64]);
    short* dst = kr + ((size_t)kh * T_SEQ + t) * HD;
    dst[d]      = f32_to_bf16(x1 * c - x2 * s);
    dst[d + 64] = f32_to_bf16(x2 * c + x1 * s);
}

// ---------------------------------------------------------------------------
// Causal flash attention R6: R5 partition efficiency + R0 balance.
// R5 counters: OccupancyPercent ~11%, makespan set by the qt=15 block doing
// 16 iters while avg block does 8.5 -> ~47% of CU-time idle by construction.
// Fix: two-phase pairing (64-row q-tiles y then 31-y): KV-128 iters per
// block = ((y>>1)+1) + (((31-y)>>1)+1) = 17, UNIFORM for all 256 blocks.
// 8 waves = 2 q-subsets (32 rows, R5's proven rows/wave) x 4 kv-quarters
// (32 cols); same B-read-per-MFMA ratios as R5. LDS 144 KB (K 64 dbuf +
// V 64 dbuf + P 16). Per-phase 4-way kv-quarter merge (max-free partials
// add) through scratch overlaid on the then-dead K/V region.
// ---------------------------------------------------------------------------
__global__ __launch_bounds__(512, 2) void attn_kernel(
    const short* __restrict__ Qr, const short* __restrict__ Kr,
    const short* __restrict__ Vt, short* __restrict__ Out)
{
    const int h = blockIdx.x;           // 0..15  (fast dim -> XCD spread)
    const int y = blockIdx.y;           // 0..15, pair index
    const int kvh = h >> 2;
    const int tid = threadIdx.x;
    const int wave = tid >> 6, lane = tid & 63;
    const int l16 = lane & 15, quad = lane >> 4;
    const int wq = wave & 1;            // q-subset (32 rows)
    const int wk = wave >> 1;           // kv-quarter (32 cols)

    __shared__ __align__(16) char smem[147456];
    short* Klds = (short*)smem;               // [2][128*128]  64 KB
    short* Vlds = (short*)(smem + 65536);     // [2][128*128]  64 KB
    short* Plds = (short*)(smem + 131072);    // [8][32*32]    16 KB

    const short* kbase = Kr + (size_t)kvh * T_SEQ * HD;
    const short* vbase = Vt + (size_t)kvh * HD * T_SEQ;

    #pragma unroll 1
    for (int ph = 0; ph < 2; ++ph) {
        const int qt32 = ph ? (31 - y) : y;        // 64-row tile index
        const int qbase = qt32 * 64 + wq * 32;
        const int n = (qt32 >> 1) + 1;             // KV-128 tiles needed
        const int ko = wk * 32;                    // this wave's kv-quarter

        bf16x8 qf[2][4];
        #pragma unroll
        for (int m = 0; m < 2; ++m) {
            const short* qrow = Qr + ((size_t)h * T_SEQ + qbase + m * 16 + l16) * HD;
            #pragma unroll
            for (int kc = 0; kc < 4; ++kc)
                qf[m][kc] = *(const bf16x8*)&qrow[kc * 32 + quad * 8];
        }
        f32x4 o[2][8] = {};
        float lsum[2][4] = {};

        __syncthreads();   // LDS free (ph0: init; ph1: merge readers done)

        {   // stage tile 0 -> buf 0 (R5-proven addressing, 512 threads)
            #pragma unroll
            for (int p = 0; p < 4; ++p) {
                int li = p * 512 + tid;
                int row = li >> 4, gs = (li & 15) ^ (row & 15);
                gl_to_lds16(kbase + (size_t)row * HD + gs * 8,
                            &Klds[(size_t)(p * 512 + wave * 64) * 8]);
            }
            #pragma unroll
            for (int p = 0; p < 4; ++p) {
                int li = p * 512 + tid;
                int row = li >> 4, gs = (li & 15) ^ (row & 15);
                gl_to_lds16(vbase + (size_t)row * T_SEQ + gs * 8,
                            &Vlds[(size_t)(p * 512 + wave * 64) * 8]);
            }
        }

        for (int t = 0; t < n; ++t) {
            asm volatile("s_waitcnt vmcnt(0)\n\ts_barrier" ::: "memory");

            if (t + 1 < n) {   // prefetch next KV-128 tile
                int kv1 = (t + 1) << 7;
                int nb = (t + 1) & 1;
                const short* ks = kbase + (size_t)kv1 * HD;
                #pragma unroll
                for (int p = 0; p < 4; ++p) {
                    int li = p * 512 + tid;
                    int row = li >> 4, gs = (li & 15) ^ (row & 15);
                    gl_to_lds16(ks + (size_t)row * HD + gs * 8,
                                &Klds[(size_t)(nb * 16384 + (p * 512 + wave * 64) * 8)]);
                }
                #pragma unroll
                for (int p = 0; p < 4; ++p) {
                    int li = p * 512 + tid;
                    int row = li >> 4, gs = (li & 15) ^ (row & 15);
                    gl_to_lds16(vbase + (size_t)row * T_SEQ + kv1 + gs * 8,
                                &Vlds[(size_t)(nb * 16384 + (p * 512 + wave * 64) * 8)]);
                }
            }

            const short* Kb = Klds + (size_t)(t & 1) * 16384;
            const short* Vb = Vlds + (size_t)(t & 1) * 16384;

            // QK^T: 32 q-rows x this wave's 32 kv cols; K-read feeds 2 row-grps
            f32x4 s[2][2];
            #pragma unroll
            for (int m = 0; m < 2; ++m)
                #pragma unroll
                for (int ni = 0; ni < 2; ++ni) s[m][ni] = (f32x4){0, 0, 0, 0};
            __builtin_amdgcn_s_setprio(1);
            #pragma unroll
            for (int ni = 0; ni < 2; ++ni)
                #pragma unroll
                for (int kc = 0; kc < 4; ++kc) {
                    bf16x8 b = *(const bf16x8*)
                        &Kb[(size_t)(ko + ni * 16 + l16) * 128 + (((kc * 4 + quad) ^ l16) * 8)];
                    s[0][ni] = __builtin_amdgcn_mfma_f32_16x16x32_bf16(qf[0][kc], b, s[0][ni], 0, 0, 0);
                    s[1][ni] = __builtin_amdgcn_mfma_f32_16x16x32_bf16(qf[1][kc], b, s[1][ni], 0, 0, 0);
                }
            __builtin_amdgcn_s_setprio(0);

            // softmax (max-free) -> Plds [32][32]/wave, chunk-xor swizzle
            if (t == n - 1) {
                int kvg0 = (t << 7) + ko;
                #pragma unroll
                for (int m = 0; m < 2; ++m)
                    #pragma unroll
                    for (int ni = 0; ni < 2; ++ni) {
                        int kvg = kvg0 + ni * 16 + l16;
                        #pragma unroll
                        for (int r = 0; r < 4; ++r) {
                            int qg = qbase + m * 16 + quad * 4 + r;
                            float p = (kvg <= qg) ? __expf(s[m][ni][r]) : 0.0f;
                            lsum[m][r] += p;
                            int prow = quad * 4 + r, pcol = ni * 16 + l16;
                            Plds[wave * 1024 + (m * 16 + prow) * 32 +
                                 (((pcol >> 3) ^ (prow & 3)) * 8) + (pcol & 7)] = f32_to_bf16(p);
                        }
                    }
            } else {
                #pragma unroll
                for (int m = 0; m < 2; ++m)
                    #pragma unroll
                    for (int ni = 0; ni < 2; ++ni)
                        #pragma unroll
                        for (int r = 0; r < 4; ++r) {
                            float p = __expf(s[m][ni][r]);
                            lsum[m][r] += p;
                            int prow = quad * 4 + r, pcol = ni * 16 + l16;
                            Plds[wave * 1024 + (m * 16 + prow) * 32 +
                                 (((pcol >> 3) ^ (prow & 3)) * 8) + (pcol & 7)] = f32_to_bf16(p);
                        }
            }
            asm volatile("s_waitcnt lgkmcnt(0)" ::: "memory");

            // PV over this wave's kv-quarter: V-read feeds 2 row-groups
            __builtin_amdgcn_s_setprio(1);
            {
                bf16x8 pa0 = *(const bf16x8*)
                    &Plds[wave * 1024 + l16 * 32 + ((quad ^ (l16 & 3)) * 8)];
                bf16x8 pa1 = *(const bf16x8*)
                    &Plds[wave * 1024 + (16 + l16) * 32 + ((quad ^ (l16 & 3)) * 8)];
                #pragma unroll
                for (int d8 = 0; d8 < 8; ++d8) {
                    bf16x8 b = *(const bf16x8*)
                        &Vb[(size_t)(d8 * 16 + l16) * 128 +
                            (((wk * 4 + quad) ^ l16) * 8)];
                    o[0][d8] = __builtin_amdgcn_mfma_f32_16x16x32_bf16(pa0, b, o[0][d8], 0, 0, 0);
                    o[1][d8] = __builtin_amdgcn_mfma_f32_16x16x32_bf16(pa1, b, o[1][d8], 0, 0, 0);
                }
            }
            __builtin_amdgcn_s_setprio(0);
        }

        // ---- merge the four kv-quarters (max-free partials just add) ----
        __syncthreads();                       // all K/V reads done
        float* Ox = (float*)smem;              // [2][3][32][132] f32 = 101376 B
        float* Lx = (float*)(smem + 101376);   // [2][3][32][16]  f32 = 12288 B
        if (wk) {
            int base = (wq * 3 + wk - 1) * 32;
            #pragma unroll
            for (int m = 0; m < 2; ++m)
                #pragma unroll
                for (int d8 = 0; d8 < 8; ++d8)
                    #pragma unroll
                    for (int r = 0; r < 4; ++r)
                        Ox[(base + m * 16 + quad * 4 + r) * 132 + d8 * 16 + l16] = o[m][d8][r];
            #pragma unroll
            for (int m = 0; m < 2; ++m)
                #pragma unroll
                for (int r = 0; r < 4; ++r)
                    Lx[(base + m * 16 + quad * 4 + r) * 16 + l16] = lsum[m][r];
        }
        __syncthreads();
        if (wk == 0) {
            #pragma unroll
            for (int j = 0; j < 3; ++j)
                #pragma unroll
                for (int m = 0; m < 2; ++m)
                    #pragma unroll
                    for (int d8 = 0; d8 < 8; ++d8)
                        #pragma unroll
                        for (int r = 0; r < 4; ++r)
                            o[m][d8][r] += Ox[((wq * 3 + j) * 32 + m * 16 + quad * 4 + r) * 132
                                              + d8 * 16 + l16];
            #pragma unroll
            for (int m = 0; m < 2; ++m)
                #pragma unroll
                for (int r = 0; r < 4; ++r) {
                    #pragma unroll
                    for (int j = 0; j < 3; ++j)
                        lsum[m][r] += Lx[((wq * 3 + j) * 32 + m * 16 + quad * 4 + r) * 16 + l16];
                    #pragma unroll
                    for (int off = 1; off < 16; off <<= 1)
                        lsum[m][r] += __shfl_xor(lsum[m][r], off);
                    lsum[m][r] = 1.0f / lsum[m][r];
                }
            #pragma unroll
            for (int m = 0; m < 2; ++m)
                #pragma unroll
                for (int d8 = 0; d8 < 8; ++d8)
                    #pragma unroll
                    for (int r = 0; r < 4; ++r) {
                        int row = qbase + m * 16 + quad * 4 + r;
                        Out[(size_t)row * D_MODEL + h * HD + d8 * 16 + l16] =
                            f32_to_bf16(o[m][d8][r] * lsum[m][r]);
                    }
        }
    }
}

// ---------------------------------------------------------------------------
extern "C" void kernel_launch(void* const* d_in, const int* in_sizes, int n_in,
                              void* d_out, int out_size, void* d_ws, size_t ws_size,
                              hipStream_t stream)
{
    const float* hs  = (const float*)d_in[0];
    const float* Wq  = (const float*)d_in[1];
    const float* Wk  = (const float*)d_in[2];
    const float* Wv  = (const float*)d_in[3];
    const float* Wo  = (const float*)d_in[4];
    const float* Wr1 = (const float*)d_in[5];
    const float* br1 = (const float*)d_in[6];
    const float* Wr2 = (const float*)d_in[7];
    const float* br2 = (const float*)d_in[8];
    float* out = (float*)d_out;

    char* w = (char*)d_ws;
    const size_t MB = 1u << 20;
    float* l2_f     = (float*)(w + 0 * MB);    // 16 MB
    short* hs_bf    = (short*)(w + 16 * MB);   // 8 MB (aliased as attn_bf later)
    short* Wq_t     = (short*)(w + 24 * MB);   // 8 MB
    short* Wkv_t    = (short*)(w + 32 * MB);   // 4 MB  [Wk^T | Wv^T]
    short* Wr1_t    = (short*)(w + 36 * MB);   // 4 MB
    short* Wo_t     = (short*)(w + 40 * MB);   // 8 MB
    short* q_bf     = (short*)(w + 48 * MB);   // 8 MB
    short* h_bf     = (short*)(w + 56 * MB);   // 4 MB
    short* fused_bf = (short*)(w + 60 * MB);   // 8 MB
    short* kv_bf    = (short*)(w + 68 * MB);   // 4 MB
    short* qr       = (short*)(w + 72 * MB);   // 8 MB (H,T,HD), roped+scaled
    short* kr       = (short*)(w + 80 * MB);   // 2 MB (KVH,T,HD), roped
    short* vr       = (short*)(w + 82 * MB);   // 2 MB (KVH,HD,T)
    float* lam_f    = (float*)(w + 84 * MB);   // 16 KB
    short* attn_bf  = hs_bf;                   // alias: hs_bf dead after q-gemm

    transpose_all_kernel<<<dim3(192, 64), 256, 0, stream>>>(
        Wq, Wk, Wv, Wr1, Wo, Wq_t, Wkv_t, Wr1_t, Wo_t);

    ema_kernel<<<dim3(T_SEQ / 128, D_MODEL / 256), 256, 0, stream>>>(hs, l2_f, hs_bf);

    // q = hs @ Wq : 16 x 32 = 512 blocks (2/CU)
    gemm_bt_kernel<128><<<dim3(16, 32), 256, 0, stream>>>(
        hs_bf, Wq_t, nullptr, q_bf, 2048, 2048, 2048, nullptr, 0);

    // h = silu(q @ Wr1 + br1) : BN=64 -> 16 x 32 = 512 blocks
    gemm_bt_kernel<64><<<dim3(16, 32), 256, 0, stream>>>(
        q_bf, Wr1_t, nullptr, h_bf, 2048, 1024, 2048, br1, 1);

    lam_kernel<<<T_SEQ, 64, 0, stream>>>(h_bf, Wr2, br2, lam_f);

    fuse_kernel<<<(T_SEQ * D_MODEL / 4) / 256, 256, 0, stream>>>(hs, l2_f, lam_f, fused_bf);

    // [k|v] = fused @ [Wk|Wv] : BN=64 -> 512 blocks
    gemm_bt_kernel<64><<<dim3(16, 32), 256, 0, stream>>>(
        fused_bf, Wkv_t, nullptr, kv_bf, 2048, 1024, 2048, nullptr, 0);

    rope_q_kernel<<<(T_SEQ * NH * 64) / 256, 256, 0, stream>>>(q_bf, qr);
    rope_k_kernel<<<(T_SEQ * NKVH * 64) / 256, 256, 0, stream>>>(kv_bf, kr);
    transpose_bf_kernel<<<dim3(16, 64), 256, 0, stream>>>(kv_bf + 512, 1024, vr, 2048);

    // 8 waves = (2 q-subsets x 4 kv-quarters), two balanced phases (y, 31-y)
    attn_kernel<<<dim3(NH, 16), 512, 0, stream>>>(qr, kr, vr, attn_bf);

    // out = attn @ Wo : 512 blocks
    gemm_bt_kernel<128><<<dim3(16, 32), 256, 0, stream>>>(
        attn_bf, Wo_t, out, nullptr, 2048, 2048, 2048, nullptr, 0);
}

// Round 7
// 313.443 us; speedup vs baseline: 1.1168x; 1.0039x over previous
//
#include <hip/hip_runtime.h>
#include <hip/hip_bf16.h>

#define T_SEQ 2048
#define D_MODEL 2048
#define NH 16
#define NKVH 4
#define HD 128

typedef __attribute__((ext_vector_type(8))) short bf16x8;
typedef __attribute__((ext_vector_type(4))) float f32x4;

static __device__ __forceinline__ short f32_to_bf16(float f) {
    unsigned u = __float_as_uint(f);
    u += 0x7fffu + ((u >> 16) & 1u);
    return (short)(u >> 16);
}
static __device__ __forceinline__ float bf16_to_f32(short s) {
    return __uint_as_float(((unsigned)(unsigned short)s) << 16);
}
static __device__ __forceinline__ void gl_to_lds16(const void* g, void* l) {
    __builtin_amdgcn_global_load_lds(
        (const __attribute__((address_space(1))) unsigned int*)g,
        (__attribute__((address_space(3))) unsigned int*)l, 16, 0, 0);
}

// ---------------------------------------------------------------------------
// Pipelined GEMM, R7: triple-buffered staging with COUNTED vmcnt (T4).
// The dbuf loop forced s_waitcnt vmcnt(0) per iter = full drain of the
// stage issued one iter earlier (~0.3-0.4us exposed latency/iter at
// ~1us/iter). tbuf keeps one stage in flight across the barrier:
//   wait vmcnt(6|4) -> barrier -> issue stage t+2 -> compute buf t%3.
// LDS: BN=128: 3x24KB=72KB x2 blocks/CU = 144 <= 160 OK; BN=64: 48KB x2.
// vmcnt retires in order, so the 6 newest outstanding are stage t+1's.
// ---------------------------------------------------------------------------
template<int BN>
__global__ __launch_bounds__(256, 2) void gemm_bt_kernel(
    const short* __restrict__ A, const short* __restrict__ Bt,
    float* __restrict__ Cf, short* __restrict__ Cb,
    int M, int N, int K, const float* __restrict__ bias, int act)
{
    constexpr int NI = BN / 64;                // 2 or 1
    constexpr int BCH = BN / 32;               // B staging instrs/wave (4 or 2)
    __shared__ short Alds[3][64 * 64];
    __shared__ short Blds[3][BN * 64];

    const int tid = threadIdx.x;
    const int wave = tid >> 6, lane = tid & 63;
    const int l16 = lane & 15, quad = lane >> 4;
    const int wn = wave * (BN / 4);
    const int m0 = blockIdx.y * 64, n0 = blockIdx.x * BN;
    const int niter = K >> 6;

    f32x4 acc[4][NI] = {};

    // prologue: stage 0 -> buf0, stage 1 -> buf1
    #pragma unroll
    for (int st = 0; st < 2; ++st) {
        int kk0 = st << 6;
        #pragma unroll
        for (int p = 0; p < 2; ++p) {
            int li = p * 256 + tid;
            int row = li >> 3, sc = li & 7;
            gl_to_lds16(A + (size_t)(m0 + row) * K + kk0 + ((sc ^ (row & 7)) * 8),
                        &Alds[st][(size_t)(p * 256 + wave * 64) * 8]);
        }
        #pragma unroll
        for (int p = 0; p < BCH; ++p) {
            int li = p * 256 + tid;
            int row = li >> 3, sc = li & 7;
            gl_to_lds16(Bt + (size_t)(n0 + row) * K + kk0 + ((sc ^ (row & 7)) * 8),
                        &Blds[st][(size_t)(p * 256 + wave * 64) * 8]);
        }
    }

    int cur = 0, stg = 2;
    for (int t = 0; t < niter; ++t) {
        if (t + 1 < niter) {        // one stage may stay in flight (counted)
            if constexpr (BN == 128)
                asm volatile("s_waitcnt vmcnt(6)\n\ts_barrier" ::: "memory");
            else
                asm volatile("s_waitcnt vmcnt(4)\n\ts_barrier" ::: "memory");
        } else {
            asm volatile("s_waitcnt vmcnt(0)\n\ts_barrier" ::: "memory");
        }

        if (t + 2 < niter) {        // issue stage t+2 into buf stg
            int k1 = (t + 2) << 6;
            #pragma unroll
            for (int p = 0; p < 2; ++p) {
                int li = p * 256 + tid;
                int row = li >> 3, sc = li & 7;
                gl_to_lds16(A + (size_t)(m0 + row) * K + k1 + ((sc ^ (row & 7)) * 8),
                            &Alds[stg][(size_t)(p * 256 + wave * 64) * 8]);
            }
            #pragma unroll
            for (int p = 0; p < BCH; ++p) {
                int li = p * 256 + tid;
                int row = li >> 3, sc = li & 7;
                gl_to_lds16(Bt + (size_t)(n0 + row) * K + k1 + ((sc ^ (row & 7)) * 8),
                            &Blds[stg][(size_t)(p * 256 + wave * 64) * 8]);
            }
        }

        const short* Ab = Alds[cur];
        const short* Bb = Blds[cur];
        #pragma unroll
        for (int kk = 0; kk < 2; ++kk) {
            bf16x8 a[4], b[NI];
            #pragma unroll
            for (int i = 0; i < 4; ++i)
                a[i] = *(const bf16x8*)
                    &Ab[(size_t)(i * 16 + l16) * 64 + (((kk * 4 + quad) ^ (l16 & 7)) * 8)];
            #pragma unroll
            for (int i = 0; i < NI; ++i)
                b[i] = *(const bf16x8*)
                    &Bb[(size_t)(wn + i * 16 + l16) * 64 + (((kk * 4 + quad) ^ (l16 & 7)) * 8)];
            #pragma unroll
            for (int mi = 0; mi < 4; ++mi)
                #pragma unroll
                for (int ni = 0; ni < NI; ++ni)
                    acc[mi][ni] = __builtin_amdgcn_mfma_f32_16x16x32_bf16(
                        a[mi], b[ni], acc[mi][ni], 0, 0, 0);
        }
        cur = (cur == 2) ? 0 : cur + 1;
        stg = (stg == 2) ? 0 : stg + 1;
    }

    #pragma unroll
    for (int mi = 0; mi < 4; ++mi) {
        #pragma unroll
        for (int ni = 0; ni < NI; ++ni) {
            int col = n0 + wn + ni * 16 + l16;
            float bv = bias ? bias[col] : 0.0f;
            #pragma unroll
            for (int r = 0; r < 4; ++r) {
                int row = m0 + mi * 16 + quad * 4 + r;
                float x = acc[mi][ni][r] + bv;
                if (act) x = x / (1.0f + __expf(-x));
                size_t o = (size_t)row * N + col;
                if (Cf) Cf[o] = x;
                if (Cb) Cb[o] = f32_to_bf16(x);
            }
        }
    }
}

// ---------------------------------------------------------------------------
// All 5 weight transposes in one launch. fp32 (2048 x C) -> bf16 (C x 2048).
// ---------------------------------------------------------------------------
__global__ __launch_bounds__(256) void transpose_all_kernel(
    const float* __restrict__ Wq, const float* __restrict__ Wk,
    const float* __restrict__ Wv, const float* __restrict__ Wr1,
    const float* __restrict__ Wo, short* __restrict__ Wq_t,
    short* __restrict__ Wkv_t, short* __restrict__ Wr1_t,
    short* __restrict__ Wo_t)
{
    __shared__ float tile[32][33];
    int bx = blockIdx.x;
    const float* src; short* dst; int ld, cb;
    if (bx < 64)       { src = Wq;  dst = Wq_t;  ld = 2048; cb = bx; }
    else if (bx < 80)  { src = Wk;  dst = Wkv_t; ld = 512;  cb = bx - 64; }
    else if (bx < 96)  { src = Wv;  dst = Wkv_t + (size_t)512 * 2048; ld = 512; cb = bx - 80; }
    else if (bx < 128) { src = Wr1; dst = Wr1_t; ld = 1024; cb = bx - 96; }
    else               { src = Wo;  dst = Wo_t;  ld = 2048; cb = bx - 128; }
    int c0 = cb * 32, r0 = blockIdx.y * 32;
    int t = threadIdx.x;
    int r = t >> 3, c4 = (t & 7) * 4;
    float4 v = *(const float4*)&src[(size_t)(r0 + r) * ld + c0 + c4];
    tile[r][c4 + 0] = v.x; tile[r][c4 + 1] = v.y;
    tile[r][c4 + 2] = v.z; tile[r][c4 + 3] = v.w;
    __syncthreads();
    short o[4];
    #pragma unroll
    for (int j = 0; j < 4; ++j) o[j] = f32_to_bf16(tile[c4 + j][r]);
    *(uint2*)&dst[(size_t)(c0 + r) * 2048 + r0 + c4] = *(const uint2*)o;
}

// bf16 transpose: src (R x C, ld) -> dst (C x R, ldd). grid (C/32, R/32).
__global__ __launch_bounds__(256) void transpose_bf_kernel(
    const short* __restrict__ src, int ld, short* __restrict__ dst, int ldd)
{
    __shared__ float tile[32][33];
    int r0 = blockIdx.y * 32, c0 = blockIdx.x * 32;
    int x = threadIdx.x & 31, y = threadIdx.x >> 5;
    #pragma unroll
    for (int i = 0; i < 4; ++i)
        tile[y + i * 8][x] = bf16_to_f32(src[(size_t)(r0 + y + i * 8) * ld + c0 + x]);
    __syncthreads();
    #pragma unroll
    for (int i = 0; i < 4; ++i)
        dst[(size_t)(c0 + y + i * 8) * ldd + r0 + x] = f32_to_bf16(tile[x][y + i * 8]);
}

// ---------------------------------------------------------------------------
// Causal prefix EMA (windowed, beta^192~2e-9) + hs -> bf16 conversion.
// ---------------------------------------------------------------------------
__global__ __launch_bounds__(256) void ema_kernel(const float* __restrict__ hs,
                                                  float* __restrict__ l2,
                                                  short* __restrict__ hs_b)
{
    int d = blockIdx.y * 256 + threadIdx.x;
    int t0 = blockIdx.x * 128;
    int ts = t0 - 192; if (ts < 0) ts = 0;
    float m = 0.0f;
    for (int tb = ts; tb < t0; tb += 16) {
        float buf[16];
        #pragma unroll
        for (int j = 0; j < 16; ++j) buf[j] = hs[(size_t)(tb + j) * D_MODEL + d];
        #pragma unroll
        for (int j = 0; j < 16; ++j) m = 0.9f * m + 0.1f * buf[j];
    }
    for (int tb = t0; tb < t0 + 128; tb += 16) {
        float buf[16];
        #pragma unroll
        for (int j = 0; j < 16; ++j) buf[j] = hs[(size_t)(tb + j) * D_MODEL + d];
        #pragma unroll
        for (int j = 0; j < 16; ++j) hs_b[(size_t)(tb + j) * D_MODEL + d] = f32_to_bf16(buf[j]);
        #pragma unroll
        for (int j = 0; j < 16; ++j) { m = 0.9f * m + 0.1f * buf[j]; buf[j] = m; }
        #pragma unroll
        for (int j = 0; j < 16; ++j) l2[(size_t)(tb + j) * D_MODEL + d] = buf[j];
    }
}

// Router head: logits = h @ Wr2 + br2, 2-way softmax. 1 wave/row.
__global__ __launch_bounds__(64) void lam_kernel(
    const short* __restrict__ h, const float* __restrict__ Wr2,
    const float* __restrict__ br2, float* __restrict__ lam)
{
    int t = blockIdx.x;
    int lane = threadIdx.x;
    float z0 = 0.0f, z1 = 0.0f;
    for (int i = lane; i < 1024; i += 64) {
        float hv = bf16_to_f32(h[(size_t)t * 1024 + i]);
        z0 += hv * Wr2[i * 2 + 0];
        z1 += hv * Wr2[i * 2 + 1];
    }
    #pragma unroll
    for (int off = 1; off < 64; off <<= 1) {
        z0 += __shfl_xor(z0, off);
        z1 += __shfl_xor(z1, off);
    }
    if (lane == 0) {
        z0 += br2[0]; z1 += br2[1];
        float mx = fmaxf(z0, z1);
        float e0 = expf(z0 - mx), e1 = expf(z1 - mx);
        float inv = 1.0f / (e0 + e1);
        lam[t * 2 + 0] = e0 * inv;
        lam[t * 2 + 1] = e1 * inv;
    }
}

// fused = lam0*hs + lam1*l2 -> bf16
__global__ void fuse_kernel(const float* __restrict__ hs, const float* __restrict__ l2,
                            const float* __restrict__ lam, short* __restrict__ fused)
{
    int idx = blockIdx.x * blockDim.x + threadIdx.x;
    int t = idx >> 9;
    float a0 = lam[t * 2 + 0], a1 = lam[t * 2 + 1];
    float4 a = ((const float4*)hs)[idx];
    float4 b = ((const float4*)l2)[idx];
    short o[4] = {f32_to_bf16(a0 * a.x + a1 * b.x), f32_to_bf16(a0 * a.y + a1 * b.y),
                  f32_to_bf16(a0 * a.z + a1 * b.z), f32_to_bf16(a0 * a.w + a1 * b.w)};
    *(uint2*)(fused + (size_t)idx * 4) = *(const uint2*)o;
}

// RoPE on q -> (H, T, HD) bf16, with 1/sqrt(HD) folded in.
__global__ void rope_q_kernel(const short* __restrict__ q, short* __restrict__ qr)
{
    int idx = blockIdx.x * blockDim.x + threadIdx.x;   // T*NH*64
    int d = idx & 63;
    int h = (idx >> 6) & 15;
    int t = idx >> 10;
    float fr = (float)t * __expf(-(float)d * 0.14391156831212787f);
    float s, c;
    sincosf(fr, &s, &c);
    const float sc = 0.08838834764831845f;  // 1/sqrt(128)
    const short* src = q + (size_t)t * D_MODEL + h * HD;
    float x1 = bf16_to_f32(src[d]) * sc, x2 = bf16_to_f32(src[d + 64]) * sc;
    short* dst = qr + ((size_t)h * T_SEQ + t) * HD;
    dst[d]      = f32_to_bf16(x1 * c - x2 * s);
    dst[d + 64] = f32_to_bf16(x2 * c + x1 * s);
}

// RoPE on k-half of kv (bf16 T x 1024) -> (KVH, T, HD) bf16.
__global__ void rope_k_kernel(const short* __restrict__ kv, short* __restrict__ kr)
{
    int idx = blockIdx.x * blockDim.x + threadIdx.x;   // T*NKVH*64
    int d = idx & 63;
    int kh = (idx >> 6) & 3;
    int t = idx >> 8;
    float fr = (float)t * __expf(-(float)d * 0.14391156831212787f);
    float s, c;
    sincosf(fr, &s, &c);
    const short* src = kv + (size_t)t * 1024 + kh * HD;
    float x1 = bf16_to_f32(src[d]), x2 = bf16_to_f32(src[d + 64]);
    short* dst = kr + ((size_t)kh * T_SEQ + t) * HD;
    dst[d]      = f32_to_bf16(x1 * c - x2 * s);
    dst[d + 64] = f32_to_bf16(x2 * c + x1 * s);
}

// ---------------------------------------------------------------------------
// Causal flash attention R7 = R6 (balanced two-phase pairing, 17 uniform
// iters, 2 q-subsets x 4 kv-quarters) + P-swizzle FIX.
// R6's P store swizzled with (prow&3) = r, which is CONSTANT per store
// instruction -> XOR did nothing per-lane; 64B row stride aliases all 4
// quads to the same banks -> 1.49M conflict cycles. Fix: slot =
// (pcol>>3) ^ r ^ quad (quad = (prow>>2)&3) -- bijective per instruction,
// quads now spread across 4 slot positions. Read side adds the matching
// ^((l16>>2)&3) term (row 16+l16 yields the same terms).
// ---------------------------------------------------------------------------
__global__ __launch_bounds__(512, 2) void attn_kernel(
    const short* __restrict__ Qr, const short* __restrict__ Kr,
    const short* __restrict__ Vt, short* __restrict__ Out)
{
    const int h = blockIdx.x;           // 0..15  (fast dim -> XCD spread)
    const int y = blockIdx.y;           // 0..15, pair index
    const int kvh = h >> 2;
    const int tid = threadIdx.x;
    const int wave = tid >> 6, lane = tid & 63;
    const int l16 = lane & 15, quad = lane >> 4;
    const int wq = wave & 1;            // q-subset (32 rows)
    const int wk = wave >> 1;           // kv-quarter (32 cols)

    __shared__ __align__(16) char smem[147456];
    short* Klds = (short*)smem;               // [2][128*128]  64 KB
    short* Vlds = (short*)(smem + 65536);     // [2][128*128]  64 KB
    short* Plds = (short*)(smem + 131072);    // [8][32*32]    16 KB

    const short* kbase = Kr + (size_t)kvh * T_SEQ * HD;
    const short* vbase = Vt + (size_t)kvh * HD * T_SEQ;

    #pragma unroll 1
    for (int ph = 0; ph < 2; ++ph) {
        const int qt32 = ph ? (31 - y) : y;        // 64-row tile index
        const int qbase = qt32 * 64 + wq * 32;
        const int n = (qt32 >> 1) + 1;             // KV-128 tiles needed
        const int ko = wk * 32;                    // this wave's kv-quarter

        bf16x8 qf[2][4];
        #pragma unroll
        for (int m = 0; m < 2; ++m) {
            const short* qrow = Qr + ((size_t)h * T_SEQ + qbase + m * 16 + l16) * HD;
            #pragma unroll
            for (int kc = 0; kc < 4; ++kc)
                qf[m][kc] = *(const bf16x8*)&qrow[kc * 32 + quad * 8];
        }
        f32x4 o[2][8] = {};
        float lsum[2][4] = {};

        __syncthreads();   // LDS free (ph0: init; ph1: merge readers done)

        {   // stage tile 0 -> buf 0 (proven addressing, 512 threads)
            #pragma unroll
            for (int p = 0; p < 4; ++p) {
                int li = p * 512 + tid;
                int row = li >> 4, gs = (li & 15) ^ (row & 15);
                gl_to_lds16(kbase + (size_t)row * HD + gs * 8,
                            &Klds[(size_t)(p * 512 + wave * 64) * 8]);
            }
            #pragma unroll
            for (int p = 0; p < 4; ++p) {
                int li = p * 512 + tid;
                int row = li >> 4, gs = (li & 15) ^ (row & 15);
                gl_to_lds16(vbase + (size_t)row * T_SEQ + gs * 8,
                            &Vlds[(size_t)(p * 512 + wave * 64) * 8]);
            }
        }

        for (int t = 0; t < n; ++t) {
            asm volatile("s_waitcnt vmcnt(0)\n\ts_barrier" ::: "memory");

            if (t + 1 < n) {   // prefetch next KV-128 tile
                int kv1 = (t + 1) << 7;
                int nb = (t + 1) & 1;
                const short* ks = kbase + (size_t)kv1 * HD;
                #pragma unroll
                for (int p = 0; p < 4; ++p) {
                    int li = p * 512 + tid;
                    int row = li >> 4, gs = (li & 15) ^ (row & 15);
                    gl_to_lds16(ks + (size_t)row * HD + gs * 8,
                                &Klds[(size_t)(nb * 16384 + (p * 512 + wave * 64) * 8)]);
                }
                #pragma unroll
                for (int p = 0; p < 4; ++p) {
                    int li = p * 512 + tid;
                    int row = li >> 4, gs = (li & 15) ^ (row & 15);
                    gl_to_lds16(vbase + (size_t)row * T_SEQ + kv1 + gs * 8,
                                &Vlds[(size_t)(nb * 16384 + (p * 512 + wave * 64) * 8)]);
                }
            }

            const short* Kb = Klds + (size_t)(t & 1) * 16384;
            const short* Vb = Vlds + (size_t)(t & 1) * 16384;

            // QK^T: 32 q-rows x this wave's 32 kv cols; K-read feeds 2 row-grps
            f32x4 s[2][2];
            #pragma unroll
            for (int m = 0; m < 2; ++m)
                #pragma unroll
                for (int ni = 0; ni < 2; ++ni) s[m][ni] = (f32x4){0, 0, 0, 0};
            __builtin_amdgcn_s_setprio(1);
            #pragma unroll
            for (int ni = 0; ni < 2; ++ni)
                #pragma unroll
                for (int kc = 0; kc < 4; ++kc) {
                    bf16x8 b = *(const bf16x8*)
                        &Kb[(size_t)(ko + ni * 16 + l16) * 128 + (((kc * 4 + quad) ^ l16) * 8)];
                    s[0][ni] = __builtin_amdgcn_mfma_f32_16x16x32_bf16(qf[0][kc], b, s[0][ni], 0, 0, 0);
                    s[1][ni] = __builtin_amdgcn_mfma_f32_16x16x32_bf16(qf[1][kc], b, s[1][ni], 0, 0, 0);
                }
            __builtin_amdgcn_s_setprio(0);

            // softmax (max-free) -> Plds [32][32]/wave; slot = c ^ r ^ quad
            if (t == n - 1) {
                int kvg0 = (t << 7) + ko;
                #pragma unroll
                for (int m = 0; m < 2; ++m)
                    #pragma unroll
                    for (int ni = 0; ni < 2; ++ni) {
                        int kvg = kvg0 + ni * 16 + l16;
                        #pragma unroll
                        for (int r = 0; r < 4; ++r) {
                            int qg = qbase + m * 16 + quad * 4 + r;
                            float p = (kvg <= qg) ? __expf(s[m][ni][r]) : 0.0f;
                            lsum[m][r] += p;
                            int prow = quad * 4 + r, pcol = ni * 16 + l16;
                            int slot = (pcol >> 3) ^ (prow & 3) ^ quad;
                            Plds[wave * 1024 + (m * 16 + prow) * 32 +
                                 slot * 8 + (pcol & 7)] = f32_to_bf16(p);
                        }
                    }
            } else {
                #pragma unroll
                for (int m = 0; m < 2; ++m)
                    #pragma unroll
                    for (int ni = 0; ni < 2; ++ni)
                        #pragma unroll
                        for (int r = 0; r < 4; ++r) {
                            float p = __expf(s[m][ni][r]);
                            lsum[m][r] += p;
                            int prow = quad * 4 + r, pcol = ni * 16 + l16;
                            int slot = (pcol >> 3) ^ (prow & 3) ^ quad;
                            Plds[wave * 1024 + (m * 16 + prow) * 32 +
                                 slot * 8 + (pcol & 7)] = f32_to_bf16(p);
                        }
            }
            asm volatile("s_waitcnt lgkmcnt(0)" ::: "memory");

            // PV over this wave's kv-quarter: V-read feeds 2 row-groups
            __builtin_amdgcn_s_setprio(1);
            {
                int slot0 = quad ^ (l16 & 3) ^ ((l16 >> 2) & 3);
                bf16x8 pa0 = *(const bf16x8*)
                    &Plds[wave * 1024 + l16 * 32 + slot0 * 8];
                bf16x8 pa1 = *(const bf16x8*)
                    &Plds[wave * 1024 + (16 + l16) * 32 + slot0 * 8];
                #pragma unroll
                for (int d8 = 0; d8 < 8; ++d8) {
                    bf16x8 b = *(const bf16x8*)
                        &Vb[(size_t)(d8 * 16 + l16) * 128 +
                            (((wk * 4 + quad) ^ l16) * 8)];
                    o[0][d8] = __builtin_amdgcn_mfma_f32_16x16x32_bf16(pa0, b, o[0][d8], 0, 0, 0);
                    o[1][d8] = __builtin_amdgcn_mfma_f32_16x16x32_bf16(pa1, b, o[1][d8], 0, 0, 0);
                }
            }
            __builtin_amdgcn_s_setprio(0);
        }

        // ---- merge the four kv-quarters (max-free partials just add) ----
        __syncthreads();                       // all K/V reads done
        float* Ox = (float*)smem;              // [2][3][32][132] f32 = 101376 B
        float* Lx = (float*)(smem + 101376);   // [2][3][32][16]  f32 = 12288 B
        if (wk) {
            int base = (wq * 3 + wk - 1) * 32;
            #pragma unroll
            for (int m = 0; m < 2; ++m)
                #pragma unroll
                for (int d8 = 0; d8 < 8; ++d8)
                    #pragma unroll
                    for (int r = 0; r < 4; ++r)
                        Ox[(base + m * 16 + quad * 4 + r) * 132 + d8 * 16 + l16] = o[m][d8][r];
            #pragma unroll
            for (int m = 0; m < 2; ++m)
                #pragma unroll
                for (int r = 0; r < 4; ++r)
                    Lx[(base + m * 16 + quad * 4 + r) * 16 + l16] = lsum[m][r];
        }
        __syncthreads();
        if (wk == 0) {
            #pragma unroll
            for (int j = 0; j < 3; ++j)
                #pragma unroll
                for (int m = 0; m < 2; ++m)
                    #pragma unroll
                    for (int d8 = 0; d8 < 8; ++d8)
                        #pragma unroll
                        for (int r = 0; r < 4; ++r)
                            o[m][d8][r] += Ox[((wq * 3 + j) * 32 + m * 16 + quad * 4 + r) * 132
                                              + d8 * 16 + l16];
            #pragma unroll
            for (int m = 0; m < 2; ++m)
                #pragma unroll
                for (int r = 0; r < 4; ++r) {
                    #pragma unroll
                    for (int j = 0; j < 3; ++j)
                        lsum[m][r] += Lx[((wq * 3 + j) * 32 + m * 16 + quad * 4 + r) * 16 + l16];
                    #pragma unroll
                    for (int off = 1; off < 16; off <<= 1)
                        lsum[m][r] += __shfl_xor(lsum[m][r], off);
                    lsum[m][r] = 1.0f / lsum[m][r];
                }
            #pragma unroll
            for (int m = 0; m < 2; ++m)
                #pragma unroll
                for (int d8 = 0; d8 < 8; ++d8)
                    #pragma unroll
                    for (int r = 0; r < 4; ++r) {
                        int row = qbase + m * 16 + quad * 4 + r;
                        Out[(size_t)row * D_MODEL + h * HD + d8 * 16 + l16] =
                            f32_to_bf16(o[m][d8][r] * lsum[m][r]);
                    }
        }
    }
}

// ---------------------------------------------------------------------------
extern "C" void kernel_launch(void* const* d_in, const int* in_sizes, int n_in,
                              void* d_out, int out_size, void* d_ws, size_t ws_size,
                              hipStream_t stream)
{
    const float* hs  = (const float*)d_in[0];
    const float* Wq  = (const float*)d_in[1];
    const float* Wk  = (const float*)d_in[2];
    const float* Wv  = (const float*)d_in[3];
    const float* Wo  = (const float*)d_in[4];
    const float* Wr1 = (const float*)d_in[5];
    const float* br1 = (const float*)d_in[6];
    const float* Wr2 = (const float*)d_in[7];
    const float* br2 = (const float*)d_in[8];
    float* out = (float*)d_out;

    char* w = (char*)d_ws;
    const size_t MB = 1u << 20;
    float* l2_f     = (float*)(w + 0 * MB);    // 16 MB
    short* hs_bf    = (short*)(w + 16 * MB);   // 8 MB (aliased as attn_bf later)
    short* Wq_t     = (short*)(w + 24 * MB);   // 8 MB
    short* Wkv_t    = (short*)(w + 32 * MB);   // 4 MB  [Wk^T | Wv^T]
    short* Wr1_t    = (short*)(w + 36 * MB);   // 4 MB
    short* Wo_t     = (short*)(w + 40 * MB);   // 8 MB
    short* q_bf     = (short*)(w + 48 * MB);   // 8 MB
    short* h_bf     = (short*)(w + 56 * MB);   // 4 MB
    short* fused_bf = (short*)(w + 60 * MB);   // 8 MB
    short* kv_bf    = (short*)(w + 68 * MB);   // 4 MB
    short* qr       = (short*)(w + 72 * MB);   // 8 MB (H,T,HD), roped+scaled
    short* kr       = (short*)(w + 80 * MB);   // 2 MB (KVH,T,HD), roped
    short* vr       = (short*)(w + 82 * MB);   // 2 MB (KVH,HD,T)
    float* lam_f    = (float*)(w + 84 * MB);   // 16 KB
    short* attn_bf  = hs_bf;                   // alias: hs_bf dead after q-gemm

    transpose_all_kernel<<<dim3(192, 64), 256, 0, stream>>>(
        Wq, Wk, Wv, Wr1, Wo, Wq_t, Wkv_t, Wr1_t, Wo_t);

    ema_kernel<<<dim3(T_SEQ / 128, D_MODEL / 256), 256, 0, stream>>>(hs, l2_f, hs_bf);

    // q = hs @ Wq : 16 x 32 = 512 blocks (2/CU)
    gemm_bt_kernel<128><<<dim3(16, 32), 256, 0, stream>>>(
        hs_bf, Wq_t, nullptr, q_bf, 2048, 2048, 2048, nullptr, 0);

    // h = silu(q @ Wr1 + br1) : BN=64 -> 16 x 32 = 512 blocks
    gemm_bt_kernel<64><<<dim3(16, 32), 256, 0, stream>>>(
        q_bf, Wr1_t, nullptr, h_bf, 2048, 1024, 2048, br1, 1);

    lam_kernel<<<T_SEQ, 64, 0, stream>>>(h_bf, Wr2, br2, lam_f);

    fuse_kernel<<<(T_SEQ * D_MODEL / 4) / 256, 256, 0, stream>>>(hs, l2_f, lam_f, fused_bf);

    // [k|v] = fused @ [Wk|Wv] : BN=64 -> 512 blocks
    gemm_bt_kernel<64><<<dim3(16, 32), 256, 0, stream>>>(
        fused_bf, Wkv_t, nullptr, kv_bf, 2048, 1024, 2048, nullptr, 0);

    rope_q_kernel<<<(T_SEQ * NH * 64) / 256, 256, 0, stream>>>(q_bf, qr);
    rope_k_kernel<<<(T_SEQ * NKVH * 64) / 256, 256, 0, stream>>>(kv_bf, kr);
    transpose_bf_kernel<<<dim3(16, 64), 256, 0, stream>>>(kv_bf + 512, 1024, vr, 2048);

    // 8 waves = (2 q-subsets x 4 kv-quarters), two balanced phases (y, 31-y)
    attn_kernel<<<dim3(NH, 16), 512, 0, stream>>>(qr, kr, vr, attn_bf);

    // out = attn @ Wo : 512 blocks
    gemm_bt_kernel<128><<<dim3(16, 32), 256, 0, stream>>>(
        attn_bf, Wo_t, out, nullptr, 2048, 2048, 2048, nullptr, 0);
}